// Round 1
// baseline (2162.803 us; speedup 1.0000x reference)
//
#include <hip/hip_runtime.h>
#include <math.h>

#define PP    1024
#define NPT   128
#define NN2   16384        // NPT*NPT
#define THRESH 0.05f
#define MAXC  1500
#define EPSD  1e-5
#define RRD   (0.1*0.1)    // double 0.010000000000000002
#define CAND_CAP 393216u
#define SEL_CAP  65536u

// ---- workspace byte offsets ----
#define OFF_HIST  0          // uint32[65536]                 -> 262144
#define OFF_HDR   262144     // uint32[16]: 0=candCount 1=selCount 2=maskU8 3=cutoff
#define OFF_STATS 262208     // double[1024*20]               -> +163840 = 426048
#define OFF_TRANS 426048     // double[1024*12]               -> +98304  = 524352
#define OFF_ICNT  524352     // int[1024]                     -> +4096   = 528448
#define OFF_POOL  528448     // float[1500*10]                -> +60000  = 588448
#define OFF_CAND  588448     // u64[CAND_CAP]                 -> +3145728= 3734176
#define OFF_SEL   3734176    // u64[SEL_CAP]                  -> +524288 = 4258464

// ---------------- quaternion Kabsch (Horn 1987) ----------------
__device__ inline void jacobi4(double A[4][4], double V[4][4]) {
  for (int i = 0; i < 4; ++i)
    for (int j = 0; j < 4; ++j) V[i][j] = (i == j) ? 1.0 : 0.0;
  const int PI_[6] = {0, 0, 0, 1, 1, 2};
  const int QI_[6] = {1, 2, 3, 2, 3, 3};
  for (int sweep = 0; sweep < 30; ++sweep) {
    double off = fabs(A[0][1]) + fabs(A[0][2]) + fabs(A[0][3]) +
                 fabs(A[1][2]) + fabs(A[1][3]) + fabs(A[2][3]);
    double dia = fabs(A[0][0]) + fabs(A[1][1]) + fabs(A[2][2]) + fabs(A[3][3]);
    if (off <= 1e-15 * (dia + 1e-300)) break;
    for (int r = 0; r < 6; ++r) {
      int p = PI_[r], q = QI_[r];
      double apq = A[p][q];
      if (fabs(apq) <= 1e-18 * (fabs(A[p][p]) + fabs(A[q][q]) + 1e-300)) continue;
      double theta = (A[q][q] - A[p][p]) / (2.0 * apq);
      double t = ((theta >= 0.0) ? 1.0 : -1.0) / (fabs(theta) + sqrt(1.0 + theta * theta));
      double c = 1.0 / sqrt(1.0 + t * t);
      double s = t * c;
      for (int k = 0; k < 4; ++k) {
        double akp = A[k][p], akq = A[k][q];
        A[k][p] = c * akp - s * akq;
        A[k][q] = s * akp + c * akq;
      }
      for (int k = 0; k < 4; ++k) {
        double apk = A[p][k], aqk = A[q][k];
        A[p][k] = c * apk - s * aqk;
        A[q][k] = s * apk + c * aqk;
      }
      for (int k = 0; k < 4; ++k) {
        double vkp = V[k][p], vkq = V[k][q];
        V[k][p] = c * vkp - s * vkq;
        V[k][q] = s * vkp + c * vkq;
      }
    }
  }
}

// sums are UN-normalized: tot=Σw, sr=Σw*ref, ss=Σw*src, m9[c*3+d]=Σw*src_c*ref_d
// Writes T12: [0..8]=R row-major (maps src->ref), [9..11]=t
__device__ inline void kabsch_from_sums(double tot, const double* sr, const double* ss,
                                        const double* m9, double* T12) {
  double den = tot + EPSD;
  double rc[3], sc[3];
  for (int c = 0; c < 3; ++c) { rc[c] = sr[c] / den; sc[c] = ss[c] / den; }
  double sb = tot / den;
  double H[3][3];
  for (int c = 0; c < 3; ++c)
    for (int d = 0; d < 3; ++d)
      H[c][d] = m9[c * 3 + d] / den - (2.0 - sb) * sc[c] * rc[d];
  if (tot < EPSD) {
    H[0][0] = 3.0; H[0][1] = 0.0; H[0][2] = 0.0;
    H[1][0] = 0.0; H[1][1] = 2.0; H[1][2] = 0.0;
    H[2][0] = 0.0; H[2][1] = 0.0; H[2][2] = 1.0;
  }
  double Sxx = H[0][0], Sxy = H[0][1], Sxz = H[0][2];
  double Syx = H[1][0], Syy = H[1][1], Syz = H[1][2];
  double Szx = H[2][0], Szy = H[2][1], Szz = H[2][2];
  double A[4][4] = {
    {Sxx + Syy + Szz, Syz - Szy,        Szx - Sxz,         Sxy - Syx},
    {Syz - Szy,       Sxx - Syy - Szz,  Sxy + Syx,         Szx + Sxz},
    {Szx - Sxz,       Sxy + Syx,       -Sxx + Syy - Szz,   Syz + Szy},
    {Sxy - Syx,       Szx + Sxz,        Syz + Szy,        -Sxx - Syy + Szz}};
  double V[4][4];
  jacobi4(A, V);
  int kb = 0; double ev = A[0][0];
  for (int i = 1; i < 4; ++i) if (A[i][i] > ev) { ev = A[i][i]; kb = i; }
  double q0 = V[0][kb], qx = V[1][kb], qy = V[2][kb], qz = V[3][kb];
  double nrm = sqrt(q0 * q0 + qx * qx + qy * qy + qz * qz);
  if (nrm < 1e-300) { q0 = 1.0; qx = qy = qz = 0.0; nrm = 1.0; }
  q0 /= nrm; qx /= nrm; qy /= nrm; qz /= nrm;
  double R[3][3];
  R[0][0] = q0*q0 + qx*qx - qy*qy - qz*qz; R[0][1] = 2.0*(qx*qy - q0*qz); R[0][2] = 2.0*(qx*qz + q0*qy);
  R[1][0] = 2.0*(qx*qy + q0*qz); R[1][1] = q0*q0 - qx*qx + qy*qy - qz*qz; R[1][2] = 2.0*(qy*qz - q0*qx);
  R[2][0] = 2.0*(qx*qz - q0*qy); R[2][1] = 2.0*(qy*qz + q0*qx); R[2][2] = q0*q0 - qx*qx - qy*qy + qz*qz;
  for (int c = 0; c < 3; ++c)
    for (int d = 0; d < 3; ++d) T12[c * 3 + d] = R[c][d];
  for (int c = 0; c < 3; ++c)
    T12[9 + c] = rc[c] - (R[c][0] * sc[0] + R[c][1] * sc[1] + R[c][2] * sc[2]);
}

// ---------------- mask dtype detection ----------------
__global__ void k_maskdetect(const unsigned* __restrict__ m, unsigned* __restrict__ hdr) {
  if (threadIdx.x == 0 && blockIdx.x == 0) {
    unsigned f = 0;
    for (int k = 0; k < 64; ++k)
      if (m[k] > 1u) { f = 1u; break; }   // bytes >1 within a word => u8 layout
    hdr[2] = f;
  }
}

// ---------------- main detect + accumulate ----------------
__global__ __launch_bounds__(256) void k_main(
    const float* __restrict__ scores, const float* __restrict__ refp,
    const float* __restrict__ srcp, const void* __restrict__ mref,
    const void* __restrict__ msrc, unsigned* __restrict__ hist,
    unsigned* __restrict__ hdr, double* __restrict__ stats,
    unsigned long long* __restrict__ cand) {
  const int p = blockIdx.x;
  const int tid = threadIdx.x;
  const int lane = tid & 63;
  __shared__ float rthr[NPT], cthr[NPT];
  __shared__ float lref[NPT * 3], lsrc[NPT * 3];
  __shared__ unsigned char lmr[NPT], lms[NPT];
  __shared__ double red[4][17];
  const unsigned maskU8 = hdr[2];
  for (int t = tid; t < NPT * 3; t += 256) {
    lref[t] = refp[p * NPT * 3 + t];
    lsrc[t] = srcp[p * NPT * 3 + t];
  }
  if (tid < NPT) {
    lmr[tid] = maskU8 ? (((const unsigned char*)mref)[p * NPT + tid] != 0)
                      : (((const int*)mref)[p * NPT + tid] != 0);
    lms[tid] = maskU8 ? (((const unsigned char*)msrc)[p * NPT + tid] != 0)
                      : (((const int*)msrc)[p * NPT + tid] != 0);
  }
  const float* S = scores + (size_t)p * NN2;
  {
    float a = -1e30f, b = -1e30f, c = -1e30f;
    if (tid < NPT) {  // column tid: top-3 over i  (coalesced across threads)
      for (int i = 0; i < NPT; ++i) {
        float v = S[i * NPT + tid];
        if (v > a) { c = b; b = a; a = v; }
        else if (v > b) { c = b; b = v; }
        else if (v > c) { c = v; }
      }
      cthr[tid] = c;
    } else {          // row tid-128: top-3 over j
      const float* row = S + (size_t)(tid - NPT) * NPT;
      for (int j = 0; j < NPT; ++j) {
        float v = row[j];
        if (v > a) { c = b; b = a; a = v; }
        else if (v > b) { c = b; b = v; }
        else if (v > c) { c = v; }
      }
      rthr[tid - NPT] = c;
    }
  }
  __syncthreads();
  double tot = 0, sr0 = 0, sr1 = 0, sr2 = 0, ss0 = 0, ss1 = 0, ss2 = 0;
  double m00 = 0, m01 = 0, m02 = 0, m10 = 0, m11 = 0, m12 = 0, m20 = 0, m21 = 0, m22 = 0;
  int cnt = 0;
  for (int it = 0; it < NN2 / 256; ++it) {
    int idx = it * 256 + tid;
    int i = idx >> 7, j = idx & (NPT - 1);
    float v = S[idx];
    float e = expf(v);
    bool corr = (v >= rthr[i]) && (v >= cthr[j]) && lmr[i] && lms[j] && (e > THRESH);
    if (corr) {
      double w = (double)e;
      double rx = lref[i * 3], ry = lref[i * 3 + 1], rz = lref[i * 3 + 2];
      double sx = lsrc[j * 3], sy = lsrc[j * 3 + 1], sz = lsrc[j * 3 + 2];
      tot += w; cnt += 1;
      sr0 += w * rx; sr1 += w * ry; sr2 += w * rz;
      ss0 += w * sx; ss1 += w * sy; ss2 += w * sz;
      double wsx = w * sx, wsy = w * sy, wsz = w * sz;
      m00 += wsx * rx; m01 += wsx * ry; m02 += wsx * rz;
      m10 += wsy * rx; m11 += wsy * ry; m12 += wsy * rz;
      m20 += wsz * rx; m21 += wsz * ry; m22 += wsz * rz;
    }
    unsigned long long mb = __ballot(corr);
    if (mb) {
      int leader = __ffsll((unsigned long long)mb) - 1;
      unsigned base = 0;
      if (lane == leader) base = atomicAdd(&hdr[0], (unsigned)__popcll(mb));
      base = __shfl(base, leader, 64);
      if (corr) {
        unsigned pos = base + (unsigned)__popcll(mb & ((1ull << lane) - 1ull));
        unsigned b = __float_as_uint(v);
        unsigned enc = (b & 0x80000000u) ? ~b : (b | 0x80000000u);  // sortable
        if (pos < CAND_CAP) {
          cand[pos] = (((unsigned long long)(~enc)) << 32) |
                      (unsigned long long)(unsigned)(p * NN2 + idx);
          atomicAdd(&hist[enc >> 16], 1u);
        }
      }
    }
  }
  double vals[17] = {tot, sr0, sr1, sr2, ss0, ss1, ss2,
                     m00, m01, m02, m10, m11, m12, m20, m21, m22, (double)cnt};
  for (int k = 0; k < 17; ++k) {
    double x = vals[k];
    for (int o = 32; o; o >>= 1) x += __shfl_down(x, o, 64);
    if (lane == 0) red[tid >> 6][k] = x;
  }
  __syncthreads();
  if (tid == 0) {
    for (int k = 0; k < 17; ++k)
      stats[p * 20 + k] = red[0][k] + red[1][k] + red[2][k] + red[3][k];
  }
}

// ---------------- histogram cutoff ----------------
__global__ __launch_bounds__(1024) void k_cutoff(const unsigned* __restrict__ hist,
                                                 unsigned* __restrict__ hdr) {
  __shared__ unsigned psum[1024];
  const int tid = threadIdx.x;
  unsigned s = 0;
  for (int b = tid * 64; b < tid * 64 + 64; ++b) s += hist[b];
  psum[tid] = s;
  __syncthreads();
  if (tid == 0) {
    unsigned acc = 0, cut = 0;
    bool done = false;
    for (int t = 1023; t >= 0 && !done; --t) {
      if (acc + psum[t] >= MAXC) {
        for (int b = t * 64 + 63; b >= t * 64; --b) {
          acc += hist[b];
          if (acc >= MAXC) { cut = (unsigned)b; done = true; break; }
        }
      } else {
        acc += psum[t];
      }
    }
    hdr[3] = done ? cut : 0u;
  }
}

// ---------------- compact above-cutoff candidates ----------------
__global__ __launch_bounds__(256) void k_compact(const unsigned long long* __restrict__ cand,
                                                 unsigned* __restrict__ hdr,
                                                 unsigned long long* __restrict__ sel) {
  const unsigned idx = blockIdx.x * 256 + threadIdx.x;
  const int lane = threadIdx.x & 63;
  const unsigned cc = hdr[0] < CAND_CAP ? hdr[0] : CAND_CAP;
  const unsigned cut = hdr[3];
  bool take = false;
  unsigned long long key = 0;
  if (idx < cc) {
    key = cand[idx];
    unsigned enc = ~(unsigned)(key >> 32);
    take = (enc >> 16) >= cut;
  }
  unsigned long long mb = __ballot(take);
  if (mb) {
    int leader = __ffsll((unsigned long long)mb) - 1;
    unsigned base = 0;
    if (lane == leader) base = atomicAdd(&hdr[1], (unsigned)__popcll(mb));
    base = __shfl(base, leader, 64);
    if (take) {
      unsigned pos = base + (unsigned)__popcll(mb & ((1ull << lane) - 1ull));
      if (pos < SEL_CAP) sel[pos] = key;
    }
  }
}

// ---------------- sort + write outputs/pool ----------------
__global__ __launch_bounds__(1024) void k_sortout(
    unsigned long long* __restrict__ sel, const unsigned* __restrict__ hdr,
    const float* __restrict__ scores, const float* __restrict__ refp,
    const float* __restrict__ srcp, float* __restrict__ pool, float* __restrict__ out) {
  const int tid = threadIdx.x;
  unsigned sc = hdr[1];
  if (sc > SEL_CAP) sc = SEL_CAP;
  unsigned n2 = 2048;
  while (n2 < sc) n2 <<= 1;
  for (unsigned t = tid; t < n2; t += 1024)
    if (t >= sc) sel[t] = 0xFFFFFFFFFFFFFFFFull;
  __syncthreads();
  for (unsigned k = 2; k <= n2; k <<= 1) {
    for (unsigned j = k >> 1; j > 0; j >>= 1) {
      for (unsigned t = tid; t < n2; t += 1024) {
        unsigned ixj = t ^ j;
        if (ixj > t) {
          unsigned long long a = sel[t], b = sel[ixj];
          bool up = ((t & k) == 0);
          if (up ? (a > b) : (a < b)) { sel[t] = b; sel[ixj] = a; }
        }
      }
      __syncthreads();
    }
  }
  for (int mm = tid; mm < MAXC; mm += 1024) {
    unsigned flat; float score; bool real;
    if ((unsigned)mm < sc) {
      unsigned long long key = sel[mm];
      flat = (unsigned)(key & 0xFFFFFFFFull);
      score = expf(scores[flat]);
      real = true;
    } else {
      flat = (unsigned)mm;  // only hit if fewer than MAXC corrs exist
      score = 0.f;
      real = false;
    }
    unsigned p = flat >> 14, rem = flat & 16383u, i = rem >> 7, j = rem & 127u;
    float rx = refp[((size_t)p * NPT + i) * 3 + 0];
    float ry = refp[((size_t)p * NPT + i) * 3 + 1];
    float rz = refp[((size_t)p * NPT + i) * 3 + 2];
    float sx = srcp[((size_t)p * NPT + j) * 3 + 0];
    float sy = srcp[((size_t)p * NPT + j) * 3 + 1];
    float sz = srcp[((size_t)p * NPT + j) * 3 + 2];
    out[mm * 3 + 0] = rx; out[mm * 3 + 1] = ry; out[mm * 3 + 2] = rz;
    out[4500 + mm * 3 + 0] = sx; out[4500 + mm * 3 + 1] = sy; out[4500 + mm * 3 + 2] = sz;
    out[9000 + mm] = score;
    pool[mm * 3 + 0] = rx; pool[mm * 3 + 1] = ry; pool[mm * 3 + 2] = rz;
    pool[4500 + mm * 3 + 0] = sx; pool[4500 + mm * 3 + 1] = sy; pool[4500 + mm * 3 + 2] = sz;
    float pad = real ? 0.f : 1e6f;
    pool[9000 + mm * 3 + 0] = sx + pad;
    pool[9000 + mm * 3 + 1] = sy + pad;
    pool[9000 + mm * 3 + 2] = sz + pad;
    pool[13500 + mm] = score;
  }
}

// ---------------- per-proposal transforms ----------------
__global__ __launch_bounds__(256) void k_transforms(const double* __restrict__ stats,
                                                    double* __restrict__ trans) {
  int p = blockIdx.x * 256 + threadIdx.x;
  if (p >= PP) return;
  const double* st = stats + p * 20;
  double sr[3] = {st[1], st[2], st[3]};
  double ss[3] = {st[4], st[5], st[6]};
  double m9[9];
  for (int k = 0; k < 9; ++k) m9[k] = st[7 + k];
  kabsch_from_sums(st[0], sr, ss, m9, trans + p * 12);
}

// ---------------- inlier counting per proposal ----------------
__global__ __launch_bounds__(256) void k_eval(const double* __restrict__ trans,
                                              const double* __restrict__ stats,
                                              const float* __restrict__ pool,
                                              int* __restrict__ icount) {
  const int p = blockIdx.x, tid = threadIdx.x, lane = tid & 63;
  __shared__ int redc[4];
  const double* T = trans + p * 12;
  double R00 = T[0], R01 = T[1], R02 = T[2], R10 = T[3], R11 = T[4], R12 = T[5];
  double R20 = T[6], R21 = T[7], R22 = T[8], t0 = T[9], t1 = T[10], t2 = T[11];
  const float* pr = pool;
  const float* pe = pool + 9000;
  int cnt = 0;
  for (int mm = tid; mm < MAXC; mm += 256) {
    double ex = pe[mm * 3], ey = pe[mm * 3 + 1], ez = pe[mm * 3 + 2];
    double ax = R00 * ex + R01 * ey + R02 * ez + t0;
    double ay = R10 * ex + R11 * ey + R12 * ez + t1;
    double az = R20 * ex + R21 * ey + R22 * ez + t2;
    double dx = pr[mm * 3] - ax, dy = pr[mm * 3 + 1] - ay, dz = pr[mm * 3 + 2] - az;
    if (dx * dx + dy * dy + dz * dz < RRD) ++cnt;
  }
  for (int o = 32; o; o >>= 1) cnt += __shfl_down(cnt, o, 64);
  if (lane == 0) redc[tid >> 6] = cnt;
  __syncthreads();
  if (tid == 0) {
    int tc = redc[0] + redc[1] + redc[2] + redc[3];
    icount[p] = (stats[p * 20 + 16] >= 3.0) ? tc : -1;
  }
}

// ---------------- argmax + iterative refinement ----------------
__global__ __launch_bounds__(256) void k_refine(const double* __restrict__ trans,
                                                const int* __restrict__ icount,
                                                const float* __restrict__ pool,
                                                float* __restrict__ out) {
  const int tid = threadIdx.x, lane = tid & 63;
  __shared__ int rc_[256], ri_[256];
  __shared__ double red[4][16];
  __shared__ double T[12];
  int bc = -2147483647, bi = 0;
  for (int idx = tid; idx < PP; idx += 256) {
    int c = icount[idx];
    if (c > bc) { bc = c; bi = idx; }
  }
  rc_[tid] = bc; ri_[tid] = bi;
  __syncthreads();
  for (int s = 128; s; s >>= 1) {
    if (tid < s) {
      int c2 = rc_[tid + s], i2 = ri_[tid + s];
      if (c2 > rc_[tid] || (c2 == rc_[tid] && i2 < ri_[tid])) { rc_[tid] = c2; ri_[tid] = i2; }
    }
    __syncthreads();
  }
  if (tid == 0) {
    int best = ri_[0];
    for (int k = 0; k < 12; ++k) T[k] = trans[best * 12 + k];
  }
  __syncthreads();
  const float* pr = pool;
  const float* ps = pool + 4500;
  const float* pe = pool + 9000;
  const float* pw = pool + 13500;
  for (int iter = 0; iter < 5; ++iter) {
    double R00 = T[0], R01 = T[1], R02 = T[2], R10 = T[3], R11 = T[4], R12 = T[5];
    double R20 = T[6], R21 = T[7], R22 = T[8], t0 = T[9], t1 = T[10], t2 = T[11];
    double tot = 0, sr0 = 0, sr1 = 0, sr2 = 0, ss0 = 0, ss1 = 0, ss2 = 0;
    double m00 = 0, m01 = 0, m02 = 0, m10 = 0, m11 = 0, m12 = 0, m20 = 0, m21 = 0, m22 = 0;
    for (int mm = tid; mm < MAXC; mm += 256) {
      double ex = pe[mm * 3], ey = pe[mm * 3 + 1], ez = pe[mm * 3 + 2];
      double ax = R00 * ex + R01 * ey + R02 * ez + t0;
      double ay = R10 * ex + R11 * ey + R12 * ez + t1;
      double az = R20 * ex + R21 * ey + R22 * ez + t2;
      double rx = pr[mm * 3], ry = pr[mm * 3 + 1], rz = pr[mm * 3 + 2];
      double dx = rx - ax, dy = ry - ay, dz = rz - az;
      if (dx * dx + dy * dy + dz * dz < RRD) {
        double w = (double)pw[mm];
        double sx = ps[mm * 3], sy = ps[mm * 3 + 1], sz = ps[mm * 3 + 2];
        tot += w;
        sr0 += w * rx; sr1 += w * ry; sr2 += w * rz;
        ss0 += w * sx; ss1 += w * sy; ss2 += w * sz;
        double wsx = w * sx, wsy = w * sy, wsz = w * sz;
        m00 += wsx * rx; m01 += wsx * ry; m02 += wsx * rz;
        m10 += wsy * rx; m11 += wsy * ry; m12 += wsy * rz;
        m20 += wsz * rx; m21 += wsz * ry; m22 += wsz * rz;
      }
    }
    double vals[16] = {tot, sr0, sr1, sr2, ss0, ss1, ss2,
                       m00, m01, m02, m10, m11, m12, m20, m21, m22};
    for (int k = 0; k < 16; ++k) {
      double x = vals[k];
      for (int o = 32; o; o >>= 1) x += __shfl_down(x, o, 64);
      if (lane == 0) red[tid >> 6][k] = x;
    }
    __syncthreads();
    if (tid == 0) {
      double s16[16];
      for (int k = 0; k < 16; ++k)
        s16[k] = red[0][k] + red[1][k] + red[2][k] + red[3][k];
      kabsch_from_sums(s16[0], s16 + 1, s16 + 4, s16 + 7, T);
    }
    __syncthreads();
  }
  if (tid == 0) {
    out[10500 + 0]  = (float)T[0]; out[10500 + 1]  = (float)T[1];
    out[10500 + 2]  = (float)T[2]; out[10500 + 3]  = (float)T[9];
    out[10500 + 4]  = (float)T[3]; out[10500 + 5]  = (float)T[4];
    out[10500 + 6]  = (float)T[5]; out[10500 + 7]  = (float)T[10];
    out[10500 + 8]  = (float)T[6]; out[10500 + 9]  = (float)T[7];
    out[10500 + 10] = (float)T[8]; out[10500 + 11] = (float)T[11];
    out[10500 + 12] = 0.f; out[10500 + 13] = 0.f;
    out[10500 + 14] = 0.f; out[10500 + 15] = 1.f;
  }
}

extern "C" void kernel_launch(void* const* d_in, const int* in_sizes, int n_in,
                              void* d_out, int out_size, void* d_ws, size_t ws_size,
                              hipStream_t stream) {
  const float* refp = (const float*)d_in[0];
  const float* srcp = (const float*)d_in[1];
  const void* mref = d_in[2];
  const void* msrc = d_in[3];
  const float* scores = (const float*)d_in[4];
  float* out = (float*)d_out;
  char* ws = (char*)d_ws;
  unsigned* hist = (unsigned*)(ws + OFF_HIST);
  unsigned* hdr = (unsigned*)(ws + OFF_HDR);
  double* stats = (double*)(ws + OFF_STATS);
  double* trans = (double*)(ws + OFF_TRANS);
  int* icount = (int*)(ws + OFF_ICNT);
  float* pool = (float*)(ws + OFF_POOL);
  unsigned long long* cand = (unsigned long long*)(ws + OFF_CAND);
  unsigned long long* sel = (unsigned long long*)(ws + OFF_SEL);

  (void)hipMemsetAsync(ws, 0, OFF_STATS, stream);  // hist + hdr
  k_maskdetect<<<1, 64, 0, stream>>>((const unsigned*)mref, hdr);
  k_main<<<PP, 256, 0, stream>>>(scores, refp, srcp, mref, msrc, hist, hdr, stats, cand);
  k_cutoff<<<1, 1024, 0, stream>>>(hist, hdr);
  k_compact<<<CAND_CAP / 256, 256, 0, stream>>>(cand, hdr, sel);
  k_sortout<<<1, 1024, 0, stream>>>(sel, hdr, scores, refp, srcp, pool, out);
  k_transforms<<<4, 256, 0, stream>>>(stats, trans);
  k_eval<<<PP, 256, 0, stream>>>(trans, stats, pool, icount);
  k_refine<<<1, 256, 0, stream>>>(trans, icount, pool, out);
}

// Round 2
// 2047.497 us; speedup vs baseline: 1.0563x; 1.0563x over previous
//
#include <hip/hip_runtime.h>
#include <math.h>

#define PP    1024
#define NPT   128
#define NN2   16384        // NPT*NPT
#define THRESH 0.05f
#define MAXC  1500
#define EPSD  1e-5
#define RRD   (0.1*0.1)
#define CAND_CAP 393216u
#define SEL_CAP  65536u
#define NEGF  -3.0e38f

// ---- workspace byte offsets ----
#define OFF_HIST  0          // uint32[65536]                 -> 262144
#define OFF_HDR   262144     // uint32[16]: 0=candCount 1=selCount 2=maskU8 3=cutoff
#define OFF_STATS 262208     // double[1024*20]               -> +163840 = 426048
#define OFF_TRANS 426048     // double[1024*12]               -> +98304  = 524352
#define OFF_ICNT  524352     // int[1024]                     -> +4096   = 528448
#define OFF_POOL  528448     // float[1500*10]                -> +60000  = 588448
#define OFF_CAND  588448     // u64[CAND_CAP]                 -> +3145728= 3734176
#define OFF_SEL   3734176    // u64[SEL_CAP]                  -> +524288 = 4258464

// ---------------- branchless top-3 helpers ----------------
__device__ inline void top3_upd(float v, float& a, float& b, float& c) {
  float m1 = fminf(a, v);
  a = fmaxf(a, v);
  float m2 = fminf(b, m1);
  b = fmaxf(b, m1);
  c = fmaxf(c, m2);
}
// merge descending triple (a,b,c) with descending triple (x0,x1,x2) -> top-3 of union
__device__ inline void merge3(float& a, float& b, float& c, float x0, float x1, float x2) {
  float z0 = fmaxf(a, x0);
  float z1 = fmaxf(fminf(a, x0), fmaxf(b, x1));
  float z2 = fmaxf(fmaxf(c, x2), fmaxf(fminf(b, x0), fminf(a, x1)));
  a = z0; b = z1; c = z2;
}

// ---------------- quaternion Kabsch (Horn 1987) ----------------
__device__ inline void jacobi4(double A[4][4], double V[4][4]) {
  for (int i = 0; i < 4; ++i)
    for (int j = 0; j < 4; ++j) V[i][j] = (i == j) ? 1.0 : 0.0;
  const int PI_[6] = {0, 0, 0, 1, 1, 2};
  const int QI_[6] = {1, 2, 3, 2, 3, 3};
  for (int sweep = 0; sweep < 30; ++sweep) {
    double off = fabs(A[0][1]) + fabs(A[0][2]) + fabs(A[0][3]) +
                 fabs(A[1][2]) + fabs(A[1][3]) + fabs(A[2][3]);
    double dia = fabs(A[0][0]) + fabs(A[1][1]) + fabs(A[2][2]) + fabs(A[3][3]);
    if (off <= 1e-15 * (dia + 1e-300)) break;
#pragma unroll
    for (int r = 0; r < 6; ++r) {
      int p = PI_[r], q = QI_[r];
      double apq = A[p][q];
      if (fabs(apq) <= 1e-18 * (fabs(A[p][p]) + fabs(A[q][q]) + 1e-300)) continue;
      double theta = (A[q][q] - A[p][p]) / (2.0 * apq);
      double t = ((theta >= 0.0) ? 1.0 : -1.0) / (fabs(theta) + sqrt(1.0 + theta * theta));
      double c = 1.0 / sqrt(1.0 + t * t);
      double s = t * c;
#pragma unroll
      for (int k = 0; k < 4; ++k) {
        double akp = A[k][p], akq = A[k][q];
        A[k][p] = c * akp - s * akq;
        A[k][q] = s * akp + c * akq;
      }
#pragma unroll
      for (int k = 0; k < 4; ++k) {
        double apk = A[p][k], aqk = A[q][k];
        A[p][k] = c * apk - s * aqk;
        A[q][k] = s * apk + c * aqk;
      }
#pragma unroll
      for (int k = 0; k < 4; ++k) {
        double vkp = V[k][p], vkq = V[k][q];
        V[k][p] = c * vkp - s * vkq;
        V[k][q] = s * vkp + c * vkq;
      }
    }
  }
}

// sums are UN-normalized: tot=Σw, sr=Σw*ref, ss=Σw*src, m9[c*3+d]=Σw*src_c*ref_d
__device__ inline void kabsch_from_sums(double tot, const double* sr, const double* ss,
                                        const double* m9, double* T12) {
  double den = tot + EPSD;
  double rc[3], sc[3];
  for (int c = 0; c < 3; ++c) { rc[c] = sr[c] / den; sc[c] = ss[c] / den; }
  double sb = tot / den;
  double H[3][3];
  for (int c = 0; c < 3; ++c)
    for (int d = 0; d < 3; ++d)
      H[c][d] = m9[c * 3 + d] / den - (2.0 - sb) * sc[c] * rc[d];
  if (tot < EPSD) {
    H[0][0] = 3.0; H[0][1] = 0.0; H[0][2] = 0.0;
    H[1][0] = 0.0; H[1][1] = 2.0; H[1][2] = 0.0;
    H[2][0] = 0.0; H[2][1] = 0.0; H[2][2] = 1.0;
  }
  double Sxx = H[0][0], Sxy = H[0][1], Sxz = H[0][2];
  double Syx = H[1][0], Syy = H[1][1], Syz = H[1][2];
  double Szx = H[2][0], Szy = H[2][1], Szz = H[2][2];
  double A[4][4] = {
    {Sxx + Syy + Szz, Syz - Szy,        Szx - Sxz,         Sxy - Syx},
    {Syz - Szy,       Sxx - Syy - Szz,  Sxy + Syx,         Szx + Sxz},
    {Szx - Sxz,       Sxy + Syx,       -Sxx + Syy - Szz,   Syz + Szy},
    {Sxy - Syx,       Szx + Sxz,        Syz + Szy,        -Sxx - Syy + Szz}};
  double V[4][4];
  jacobi4(A, V);
  int kb = 0; double ev = A[0][0];
  for (int i = 1; i < 4; ++i) if (A[i][i] > ev) { ev = A[i][i]; kb = i; }
  double q0 = V[0][kb], qx = V[1][kb], qy = V[2][kb], qz = V[3][kb];
  double nrm = sqrt(q0 * q0 + qx * qx + qy * qy + qz * qz);
  if (nrm < 1e-300) { q0 = 1.0; qx = qy = qz = 0.0; nrm = 1.0; }
  q0 /= nrm; qx /= nrm; qy /= nrm; qz /= nrm;
  double R[3][3];
  R[0][0] = q0*q0 + qx*qx - qy*qy - qz*qz; R[0][1] = 2.0*(qx*qy - q0*qz); R[0][2] = 2.0*(qx*qz + q0*qy);
  R[1][0] = 2.0*(qx*qy + q0*qz); R[1][1] = q0*q0 - qx*qx + qy*qy - qz*qz; R[1][2] = 2.0*(qy*qz - q0*qx);
  R[2][0] = 2.0*(qx*qz - q0*qy); R[2][1] = 2.0*(qy*qz + q0*qx); R[2][2] = q0*q0 - qx*qx - qy*qy + qz*qz;
  for (int c = 0; c < 3; ++c)
    for (int d = 0; d < 3; ++d) T12[c * 3 + d] = R[c][d];
  for (int c = 0; c < 3; ++c)
    T12[9 + c] = rc[c] - (R[c][0] * sc[0] + R[c][1] * sc[1] + R[c][2] * sc[2]);
}

// ---------------- mask dtype detection ----------------
__global__ void k_maskdetect(const unsigned* __restrict__ m, unsigned* __restrict__ hdr) {
  if (threadIdx.x == 0 && blockIdx.x == 0) {
    unsigned f = 0;
    for (int k = 0; k < 64; ++k)
      if (m[k] > 1u) { f = 1u; break; }
    hdr[2] = f;
  }
}

// ---------------- main detect + accumulate (coalesced + LDS chunked) ----------------
__global__ __launch_bounds__(256, 2) void k_main(
    const float* __restrict__ scores, const float* __restrict__ refp,
    const float* __restrict__ srcp, const void* __restrict__ mref,
    const void* __restrict__ msrc, unsigned* __restrict__ hist,
    unsigned* __restrict__ hdr, double* __restrict__ stats,
    unsigned long long* __restrict__ cand) {
  const int p = blockIdx.x;
  const int tid = threadIdx.x;
  const int lane = tid & 63;
  __shared__ float tile[32 * 132];        // 32-row chunk, stride 132 (conflict-safe)
  __shared__ float colpart[2][NPT][3];
  __shared__ float rpart[32][8][3];
  __shared__ float rthr[NPT], cthr[NPT];
  __shared__ float lref[NPT * 3], lsrc[NPT * 3];
  __shared__ unsigned char lmr[NPT], lms[NPT];
  __shared__ double red[4][17];
  const unsigned maskU8 = hdr[2];
  for (int t = tid; t < NPT * 3; t += 256) {
    lref[t] = refp[p * NPT * 3 + t];
    lsrc[t] = srcp[p * NPT * 3 + t];
  }
  if (tid < NPT) {
    lmr[tid] = maskU8 ? (((const unsigned char*)mref)[p * NPT + tid] != 0)
                      : (((const int*)mref)[p * NPT + tid] != 0);
    lms[tid] = maskU8 ? (((const unsigned char*)msrc)[p * NPT + tid] != 0)
                      : (((const int*)msrc)[p * NPT + tid] != 0);
  }
  const float* S = scores + (size_t)p * NN2;
  const int col = tid & 127;
  const int half = tid >> 7;
  // ---- Pass A: column top-3, coalesced streaming, branchless ----
  {
    float a = NEGF, b = NEGF, c = NEGF;
    const float* base = S + (size_t)half * 64 * NPT + col;
#pragma unroll 8
    for (int it = 0; it < 64; ++it)
      top3_upd(base[it * NPT], a, b, c);
    colpart[half][col][0] = a; colpart[half][col][1] = b; colpart[half][col][2] = c;
  }
  __syncthreads();
  if (tid < NPT) {
    float a = colpart[0][tid][0], b = colpart[0][tid][1], c = colpart[0][tid][2];
    merge3(a, b, c, colpart[1][tid][0], colpart[1][tid][1], colpart[1][tid][2]);
    cthr[tid] = c;
  }
  __syncthreads();
  // ---- Pass B: 4 chunks of 32 rows ----
  double tot = 0, sr0 = 0, sr1 = 0, sr2 = 0, ss0 = 0, ss1 = 0, ss2 = 0;
  double m00 = 0, m01 = 0, m02 = 0, m10 = 0, m11 = 0, m12 = 0, m20 = 0, m21 = 0, m22 = 0;
  int cnt = 0;
  for (int ch = 0; ch < 4; ++ch) {
    const int cb = ch << 5;
    {  // stage 32 rows, coalesced global -> conflict-free LDS
      const float* gsrc = S + (size_t)(cb + half * 16) * NPT + col;
      float* ldst = tile + (half * 16) * 132 + col;
#pragma unroll
      for (int i = 0; i < 16; ++i)
        ldst[i * 132] = gsrc[i * NPT];
    }
    __syncthreads();
    {  // row top-3 partials: 8 threads/row x 16 cols
      const int rl = tid >> 3, o = tid & 7;
      float a = NEGF, b = NEGF, c = NEGF;
      const float* tr = tile + rl * 132 + o * 16;
#pragma unroll
      for (int k = 0; k < 16; ++k) top3_upd(tr[k], a, b, c);
      rpart[rl][o][0] = a; rpart[rl][o][1] = b; rpart[rl][o][2] = c;
    }
    __syncthreads();
    if (tid < 32) {
      float a = rpart[tid][0][0], b = rpart[tid][0][1], c = rpart[tid][0][2];
#pragma unroll
      for (int o = 1; o < 8; ++o)
        merge3(a, b, c, rpart[tid][o][0], rpart[tid][o][1], rpart[tid][o][2]);
      rthr[cb + tid] = c;
    }
    __syncthreads();
    // corr scan over the chunk (reads LDS only)
    for (int itc = 0; itc < 16; ++itc) {
      int lidx = itc * 256 + tid;
      int rl = lidx >> 7, j = lidx & 127;
      int i = cb + rl;
      float v = tile[rl * 132 + j];
      float e = expf(v);
      bool corr = (v >= rthr[i]) && (v >= cthr[j]) && lmr[i] && lms[j] && (e > THRESH);
      if (corr) {
        double w = (double)e;
        double rx = lref[i * 3], ry = lref[i * 3 + 1], rz = lref[i * 3 + 2];
        double sx = lsrc[j * 3], sy = lsrc[j * 3 + 1], sz = lsrc[j * 3 + 2];
        tot += w; cnt += 1;
        sr0 += w * rx; sr1 += w * ry; sr2 += w * rz;
        ss0 += w * sx; ss1 += w * sy; ss2 += w * sz;
        double wsx = w * sx, wsy = w * sy, wsz = w * sz;
        m00 += wsx * rx; m01 += wsx * ry; m02 += wsx * rz;
        m10 += wsy * rx; m11 += wsy * ry; m12 += wsy * rz;
        m20 += wsz * rx; m21 += wsz * ry; m22 += wsz * rz;
      }
      unsigned long long mb = __ballot(corr);
      if (mb) {
        int leader = __ffsll((unsigned long long)mb) - 1;
        unsigned base = 0;
        if (lane == leader) base = atomicAdd(&hdr[0], (unsigned)__popcll(mb));
        base = __shfl(base, leader, 64);
        if (corr) {
          unsigned pos = base + (unsigned)__popcll(mb & ((1ull << lane) - 1ull));
          unsigned bb = __float_as_uint(v);
          unsigned enc = (bb & 0x80000000u) ? ~bb : (bb | 0x80000000u);
          if (pos < CAND_CAP) {
            cand[pos] = (((unsigned long long)(~enc)) << 32) |
                        (unsigned long long)(unsigned)(p * NN2 + i * NPT + j);
            atomicAdd(&hist[enc >> 16], 1u);
          }
        }
      }
    }
    __syncthreads();
  }
  double vals[17] = {tot, sr0, sr1, sr2, ss0, ss1, ss2,
                     m00, m01, m02, m10, m11, m12, m20, m21, m22, (double)cnt};
#pragma unroll
  for (int k = 0; k < 17; ++k) {
    double x = vals[k];
    for (int o = 32; o; o >>= 1) x += __shfl_down(x, o, 64);
    if (lane == 0) red[tid >> 6][k] = x;
  }
  __syncthreads();
  if (tid == 0) {
    for (int k = 0; k < 17; ++k)
      stats[p * 20 + k] = red[0][k] + red[1][k] + red[2][k] + red[3][k];
  }
}

// ---------------- histogram cutoff (uint4 + parallel suffix scan) ----------------
__global__ __launch_bounds__(1024) void k_cutoff(const unsigned* __restrict__ hist,
                                                 unsigned* __restrict__ hdr) {
  __shared__ unsigned ss[1024];
  const int tid = threadIdx.x;
  unsigned s = 0;
  const uint4* h4 = (const uint4*)hist + tid * 16;
#pragma unroll
  for (int q = 0; q < 16; ++q) {
    uint4 h = h4[q];
    s += h.x + h.y + h.z + h.w;
  }
  ss[tid] = s;
  __syncthreads();
  for (int off = 1; off < 1024; off <<= 1) {
    unsigned v = ss[tid];
    unsigned add = (tid + off < 1024) ? ss[tid + off] : 0u;
    __syncthreads();
    ss[tid] = v + add;
    __syncthreads();
  }
  unsigned after = (tid < 1023) ? ss[tid + 1] : 0u;
  if (after < MAXC && after + s >= MAXC) {   // unique thread
    unsigned acc = after;
    for (int b = tid * 64 + 63; b >= tid * 64; --b) {
      acc += hist[b];
      if (acc >= MAXC) { hdr[3] = (unsigned)b; break; }
    }
  }
  // if total < MAXC no thread fires: hdr[3] stays 0 from memset (same as before)
}

// ---------------- compact above-cutoff candidates ----------------
__global__ __launch_bounds__(256) void k_compact(const unsigned long long* __restrict__ cand,
                                                 unsigned* __restrict__ hdr,
                                                 unsigned long long* __restrict__ sel) {
  const unsigned idx = blockIdx.x * 256 + threadIdx.x;
  const int lane = threadIdx.x & 63;
  const unsigned cc = hdr[0] < CAND_CAP ? hdr[0] : CAND_CAP;
  const unsigned cut = hdr[3];
  bool take = false;
  unsigned long long key = 0;
  if (idx < cc) {
    key = cand[idx];
    unsigned enc = ~(unsigned)(key >> 32);
    take = (enc >> 16) >= cut;
  }
  unsigned long long mb = __ballot(take);
  if (mb) {
    int leader = __ffsll((unsigned long long)mb) - 1;
    unsigned base = 0;
    if (lane == leader) base = atomicAdd(&hdr[1], (unsigned)__popcll(mb));
    base = __shfl(base, leader, 64);
    if (take) {
      unsigned pos = base + (unsigned)__popcll(mb & ((1ull << lane) - 1ull));
      if (pos < SEL_CAP) sel[pos] = key;
    }
  }
}

// ---------------- sort (LDS bitonic) + write outputs/pool ----------------
__global__ __launch_bounds__(1024) void k_sortout(
    unsigned long long* __restrict__ sel, const unsigned* __restrict__ hdr,
    const float* __restrict__ scores, const float* __restrict__ refp,
    const float* __restrict__ srcp, float* __restrict__ pool, float* __restrict__ out) {
  __shared__ unsigned long long ls[4096];
  const int tid = threadIdx.x;
  unsigned sc = hdr[1];
  if (sc > SEL_CAP) sc = SEL_CAP;
  unsigned n2 = 2048;
  while (n2 < sc) n2 <<= 1;
  const bool uselds = (n2 <= 4096);
  if (uselds) {
    for (unsigned t = tid; t < n2; t += 1024)
      ls[t] = (t < sc) ? sel[t] : 0xFFFFFFFFFFFFFFFFull;
    __syncthreads();
    for (unsigned k = 2; k <= n2; k <<= 1) {
      for (unsigned j = k >> 1; j; j >>= 1) {
        for (unsigned t = tid; t < n2; t += 1024) {
          unsigned ixj = t ^ j;
          if (ixj > t) {
            unsigned long long A = ls[t], B = ls[ixj];
            bool up = ((t & k) == 0);
            if (up ? (A > B) : (A < B)) { ls[t] = B; ls[ixj] = A; }
          }
        }
        __syncthreads();
      }
    }
  } else {  // fallback: global bitonic (sc > 4096 — practically never)
    for (unsigned t = tid; t < n2; t += 1024)
      if (t >= sc) sel[t] = 0xFFFFFFFFFFFFFFFFull;
    __syncthreads();
    for (unsigned k = 2; k <= n2; k <<= 1) {
      for (unsigned j = k >> 1; j; j >>= 1) {
        for (unsigned t = tid; t < n2; t += 1024) {
          unsigned ixj = t ^ j;
          if (ixj > t) {
            unsigned long long A = sel[t], B = sel[ixj];
            bool up = ((t & k) == 0);
            if (up ? (A > B) : (A < B)) { sel[t] = B; sel[ixj] = A; }
          }
        }
        __syncthreads();
      }
    }
  }
  for (int mm = tid; mm < MAXC; mm += 1024) {
    unsigned flat; float score; bool real;
    if ((unsigned)mm < sc) {
      unsigned long long key = uselds ? ls[mm] : sel[mm];
      flat = (unsigned)(key & 0xFFFFFFFFull);
      score = expf(scores[flat]);
      real = true;
    } else {
      flat = (unsigned)mm;
      score = 0.f;
      real = false;
    }
    unsigned p = flat >> 14, rem = flat & 16383u, i = rem >> 7, j = rem & 127u;
    float rx = refp[((size_t)p * NPT + i) * 3 + 0];
    float ry = refp[((size_t)p * NPT + i) * 3 + 1];
    float rz = refp[((size_t)p * NPT + i) * 3 + 2];
    float sx = srcp[((size_t)p * NPT + j) * 3 + 0];
    float sy = srcp[((size_t)p * NPT + j) * 3 + 1];
    float sz = srcp[((size_t)p * NPT + j) * 3 + 2];
    out[mm * 3 + 0] = rx; out[mm * 3 + 1] = ry; out[mm * 3 + 2] = rz;
    out[4500 + mm * 3 + 0] = sx; out[4500 + mm * 3 + 1] = sy; out[4500 + mm * 3 + 2] = sz;
    out[9000 + mm] = score;
    pool[mm * 3 + 0] = rx; pool[mm * 3 + 1] = ry; pool[mm * 3 + 2] = rz;
    pool[4500 + mm * 3 + 0] = sx; pool[4500 + mm * 3 + 1] = sy; pool[4500 + mm * 3 + 2] = sz;
    float pad = real ? 0.f : 1e6f;
    pool[9000 + mm * 3 + 0] = sx + pad;
    pool[9000 + mm * 3 + 1] = sy + pad;
    pool[9000 + mm * 3 + 2] = sz + pad;
    pool[13500 + mm] = score;
  }
}

// ---------------- per-proposal transforms ----------------
__global__ __launch_bounds__(64, 1) void k_transforms(const double* __restrict__ stats,
                                                      double* __restrict__ trans) {
  int p = blockIdx.x * 64 + threadIdx.x;
  if (p >= PP) return;
  const double* st = stats + p * 20;
  double sr[3] = {st[1], st[2], st[3]};
  double ss[3] = {st[4], st[5], st[6]};
  double m9[9];
  for (int k = 0; k < 9; ++k) m9[k] = st[7 + k];
  kabsch_from_sums(st[0], sr, ss, m9, trans + p * 12);
}

// ---------------- inlier counting per proposal ----------------
__global__ __launch_bounds__(256) void k_eval(const double* __restrict__ trans,
                                              const double* __restrict__ stats,
                                              const float* __restrict__ pool,
                                              int* __restrict__ icount) {
  const int p = blockIdx.x, tid = threadIdx.x, lane = tid & 63;
  __shared__ int redc[4];
  const double* T = trans + p * 12;
  double R00 = T[0], R01 = T[1], R02 = T[2], R10 = T[3], R11 = T[4], R12 = T[5];
  double R20 = T[6], R21 = T[7], R22 = T[8], t0 = T[9], t1 = T[10], t2 = T[11];
  const float* pr = pool;
  const float* pe = pool + 9000;
  int cnt = 0;
  for (int mm = tid; mm < MAXC; mm += 256) {
    double ex = pe[mm * 3], ey = pe[mm * 3 + 1], ez = pe[mm * 3 + 2];
    double ax = R00 * ex + R01 * ey + R02 * ez + t0;
    double ay = R10 * ex + R11 * ey + R12 * ez + t1;
    double az = R20 * ex + R21 * ey + R22 * ez + t2;
    double dx = pr[mm * 3] - ax, dy = pr[mm * 3 + 1] - ay, dz = pr[mm * 3 + 2] - az;
    if (dx * dx + dy * dy + dz * dz < RRD) ++cnt;
  }
  for (int o = 32; o; o >>= 1) cnt += __shfl_down(cnt, o, 64);
  if (lane == 0) redc[tid >> 6] = cnt;
  __syncthreads();
  if (tid == 0) {
    int tc = redc[0] + redc[1] + redc[2] + redc[3];
    icount[p] = (stats[p * 20 + 16] >= 3.0) ? tc : -1;
  }
}

// ---------------- argmax + iterative refinement ----------------
__global__ __launch_bounds__(256, 1) void k_refine(const double* __restrict__ trans,
                                                   const int* __restrict__ icount,
                                                   const float* __restrict__ pool,
                                                   float* __restrict__ out) {
  const int tid = threadIdx.x, lane = tid & 63;
  __shared__ int rc_[256], ri_[256];
  __shared__ double red[4][16];
  __shared__ double T[12];
  int bc = -2147483647, bi = 0;
  for (int idx = tid; idx < PP; idx += 256) {
    int c = icount[idx];
    if (c > bc) { bc = c; bi = idx; }
  }
  rc_[tid] = bc; ri_[tid] = bi;
  __syncthreads();
  for (int s = 128; s; s >>= 1) {
    if (tid < s) {
      int c2 = rc_[tid + s], i2 = ri_[tid + s];
      if (c2 > rc_[tid] || (c2 == rc_[tid] && i2 < ri_[tid])) { rc_[tid] = c2; ri_[tid] = i2; }
    }
    __syncthreads();
  }
  if (tid == 0) {
    int best = ri_[0];
    for (int k = 0; k < 12; ++k) T[k] = trans[best * 12 + k];
  }
  __syncthreads();
  const float* pr = pool;
  const float* ps = pool + 4500;
  const float* pe = pool + 9000;
  const float* pw = pool + 13500;
  for (int iter = 0; iter < 5; ++iter) {
    double R00 = T[0], R01 = T[1], R02 = T[2], R10 = T[3], R11 = T[4], R12 = T[5];
    double R20 = T[6], R21 = T[7], R22 = T[8], t0 = T[9], t1 = T[10], t2 = T[11];
    double tot = 0, sr0 = 0, sr1 = 0, sr2 = 0, ss0 = 0, ss1 = 0, ss2 = 0;
    double m00 = 0, m01 = 0, m02 = 0, m10 = 0, m11 = 0, m12 = 0, m20 = 0, m21 = 0, m22 = 0;
    for (int mm = tid; mm < MAXC; mm += 256) {
      double ex = pe[mm * 3], ey = pe[mm * 3 + 1], ez = pe[mm * 3 + 2];
      double ax = R00 * ex + R01 * ey + R02 * ez + t0;
      double ay = R10 * ex + R11 * ey + R12 * ez + t1;
      double az = R20 * ex + R21 * ey + R22 * ez + t2;
      double rx = pr[mm * 3], ry = pr[mm * 3 + 1], rz = pr[mm * 3 + 2];
      double dx = rx - ax, dy = ry - ay, dz = rz - az;
      if (dx * dx + dy * dy + dz * dz < RRD) {
        double w = (double)pw[mm];
        double sx = ps[mm * 3], sy = ps[mm * 3 + 1], sz = ps[mm * 3 + 2];
        tot += w;
        sr0 += w * rx; sr1 += w * ry; sr2 += w * rz;
        ss0 += w * sx; ss1 += w * sy; ss2 += w * sz;
        double wsx = w * sx, wsy = w * sy, wsz = w * sz;
        m00 += wsx * rx; m01 += wsx * ry; m02 += wsx * rz;
        m10 += wsy * rx; m11 += wsy * ry; m12 += wsy * rz;
        m20 += wsz * rx; m21 += wsz * ry; m22 += wsz * rz;
      }
    }
    double vals[16] = {tot, sr0, sr1, sr2, ss0, ss1, ss2,
                       m00, m01, m02, m10, m11, m12, m20, m21, m22};
#pragma unroll
    for (int k = 0; k < 16; ++k) {
      double x = vals[k];
      for (int o = 32; o; o >>= 1) x += __shfl_down(x, o, 64);
      if (lane == 0) red[tid >> 6][k] = x;
    }
    __syncthreads();
    if (tid == 0) {
      double s16[16];
      for (int k = 0; k < 16; ++k)
        s16[k] = red[0][k] + red[1][k] + red[2][k] + red[3][k];
      kabsch_from_sums(s16[0], s16 + 1, s16 + 4, s16 + 7, T);
    }
    __syncthreads();
  }
  if (tid == 0) {
    out[10500 + 0]  = (float)T[0]; out[10500 + 1]  = (float)T[1];
    out[10500 + 2]  = (float)T[2]; out[10500 + 3]  = (float)T[9];
    out[10500 + 4]  = (float)T[3]; out[10500 + 5]  = (float)T[4];
    out[10500 + 6]  = (float)T[5]; out[10500 + 7]  = (float)T[10];
    out[10500 + 8]  = (float)T[6]; out[10500 + 9]  = (float)T[7];
    out[10500 + 10] = (float)T[8]; out[10500 + 11] = (float)T[11];
    out[10500 + 12] = 0.f; out[10500 + 13] = 0.f;
    out[10500 + 14] = 0.f; out[10500 + 15] = 1.f;
  }
}

extern "C" void kernel_launch(void* const* d_in, const int* in_sizes, int n_in,
                              void* d_out, int out_size, void* d_ws, size_t ws_size,
                              hipStream_t stream) {
  const float* refp = (const float*)d_in[0];
  const float* srcp = (const float*)d_in[1];
  const void* mref = d_in[2];
  const void* msrc = d_in[3];
  const float* scores = (const float*)d_in[4];
  float* out = (float*)d_out;
  char* ws = (char*)d_ws;
  unsigned* hist = (unsigned*)(ws + OFF_HIST);
  unsigned* hdr = (unsigned*)(ws + OFF_HDR);
  double* stats = (double*)(ws + OFF_STATS);
  double* trans = (double*)(ws + OFF_TRANS);
  int* icount = (int*)(ws + OFF_ICNT);
  float* pool = (float*)(ws + OFF_POOL);
  unsigned long long* cand = (unsigned long long*)(ws + OFF_CAND);
  unsigned long long* sel = (unsigned long long*)(ws + OFF_SEL);

  (void)hipMemsetAsync(ws, 0, OFF_STATS, stream);  // hist + hdr
  k_maskdetect<<<1, 64, 0, stream>>>((const unsigned*)mref, hdr);
  k_main<<<PP, 256, 0, stream>>>(scores, refp, srcp, mref, msrc, hist, hdr, stats, cand);
  k_cutoff<<<1, 1024, 0, stream>>>(hist, hdr);
  k_compact<<<CAND_CAP / 256, 256, 0, stream>>>(cand, hdr, sel);
  k_sortout<<<1, 1024, 0, stream>>>(sel, hdr, scores, refp, srcp, pool, out);
  k_transforms<<<16, 64, 0, stream>>>(stats, trans);
  k_eval<<<PP, 256, 0, stream>>>(trans, stats, pool, icount);
  k_refine<<<1, 256, 0, stream>>>(trans, icount, pool, out);
}

// Round 3
// 592.643 us; speedup vs baseline: 3.6494x; 3.4549x over previous
//
#include <hip/hip_runtime.h>
#include <math.h>

#define PP    1024
#define NPT   128
#define NN2   16384        // NPT*NPT
#define THRESH 0.05f
#define MAXC  1500
#define EPSD  1e-5
#define RRD   (0.1*0.1)
#define CAND_CAP 393216u
#define SEL_CAP  65536u
#define NEGF  -3.0e38f
#define MAXCORR_PB 384     // hard cap: row-top3 => <=3*128 corrs per proposal

// ---- workspace byte offsets ----
#define OFF_HIST  0          // uint32[65536]                 -> 262144
#define OFF_HDR   262144     // uint32[16]: 0=candCount 1=selCount 2=maskU8 3=cutoff
#define OFF_STATS 262208     // double[1024*20]               -> +163840 = 426048
#define OFF_TRANS 426048     // double[1024*12]               -> +98304  = 524352
#define OFF_ICNT  524352     // int[1024]                     -> +4096   = 528448
#define OFF_POOL  528448     // float[1500*10]                -> +60000  = 588448
#define OFF_CAND  588448     // u64[CAND_CAP]                 -> +3145728= 3734176
#define OFF_SEL   3734176    // u64[SEL_CAP]                  -> +524288 = 4258464
#define OFF_RTHR  4258464    // float[1024*128]               -> +524288 = 4782752
#define OFF_CTHR  4782752    // float[1024*128]               -> +524288 = 5307040

// ---------------- branchless top-3 helpers ----------------
__device__ inline void top3_upd(float v, float& a, float& b, float& c) {
  float m1 = fminf(a, v);
  a = fmaxf(a, v);
  float m2 = fminf(b, m1);
  b = fmaxf(b, m1);
  c = fmaxf(c, m2);
}
__device__ inline void merge3(float& a, float& b, float& c, float x0, float x1, float x2) {
  float z0 = fmaxf(a, x0);
  float z1 = fmaxf(fminf(a, x0), fmaxf(b, x1));
  float z2 = fmaxf(fmaxf(c, x2), fmaxf(fminf(b, x0), fminf(a, x1)));
  a = z0; b = z1; c = z2;
}

// ---------------- quaternion Kabsch (Horn 1987) ----------------
__device__ inline void jacobi4(double A[4][4], double V[4][4]) {
  for (int i = 0; i < 4; ++i)
    for (int j = 0; j < 4; ++j) V[i][j] = (i == j) ? 1.0 : 0.0;
  const int PI_[6] = {0, 0, 0, 1, 1, 2};
  const int QI_[6] = {1, 2, 3, 2, 3, 3};
  for (int sweep = 0; sweep < 30; ++sweep) {
    double off = fabs(A[0][1]) + fabs(A[0][2]) + fabs(A[0][3]) +
                 fabs(A[1][2]) + fabs(A[1][3]) + fabs(A[2][3]);
    double dia = fabs(A[0][0]) + fabs(A[1][1]) + fabs(A[2][2]) + fabs(A[3][3]);
    if (off <= 1e-15 * (dia + 1e-300)) break;
#pragma unroll
    for (int r = 0; r < 6; ++r) {
      int p = PI_[r], q = QI_[r];
      double apq = A[p][q];
      if (fabs(apq) <= 1e-18 * (fabs(A[p][p]) + fabs(A[q][q]) + 1e-300)) continue;
      double theta = (A[q][q] - A[p][p]) / (2.0 * apq);
      double t = ((theta >= 0.0) ? 1.0 : -1.0) / (fabs(theta) + sqrt(1.0 + theta * theta));
      double c = 1.0 / sqrt(1.0 + t * t);
      double s = t * c;
#pragma unroll
      for (int k = 0; k < 4; ++k) {
        double akp = A[k][p], akq = A[k][q];
        A[k][p] = c * akp - s * akq;
        A[k][q] = s * akp + c * akq;
      }
#pragma unroll
      for (int k = 0; k < 4; ++k) {
        double apk = A[p][k], aqk = A[q][k];
        A[p][k] = c * apk - s * aqk;
        A[q][k] = s * apk + c * aqk;
      }
#pragma unroll
      for (int k = 0; k < 4; ++k) {
        double vkp = V[k][p], vkq = V[k][q];
        V[k][p] = c * vkp - s * vkq;
        V[k][q] = s * vkp + c * vkq;
      }
    }
  }
}

__device__ inline void kabsch_from_sums(double tot, const double* sr, const double* ss,
                                        const double* m9, double* T12) {
  double den = tot + EPSD;
  double rc[3], sc[3];
  for (int c = 0; c < 3; ++c) { rc[c] = sr[c] / den; sc[c] = ss[c] / den; }
  double sb = tot / den;
  double H[3][3];
  for (int c = 0; c < 3; ++c)
    for (int d = 0; d < 3; ++d)
      H[c][d] = m9[c * 3 + d] / den - (2.0 - sb) * sc[c] * rc[d];
  if (tot < EPSD) {
    H[0][0] = 3.0; H[0][1] = 0.0; H[0][2] = 0.0;
    H[1][0] = 0.0; H[1][1] = 2.0; H[1][2] = 0.0;
    H[2][0] = 0.0; H[2][1] = 0.0; H[2][2] = 1.0;
  }
  double Sxx = H[0][0], Sxy = H[0][1], Sxz = H[0][2];
  double Syx = H[1][0], Syy = H[1][1], Syz = H[1][2];
  double Szx = H[2][0], Szy = H[2][1], Szz = H[2][2];
  double A[4][4] = {
    {Sxx + Syy + Szz, Syz - Szy,        Szx - Sxz,         Sxy - Syx},
    {Syz - Szy,       Sxx - Syy - Szz,  Sxy + Syx,         Szx + Sxz},
    {Szx - Sxz,       Sxy + Syx,       -Sxx + Syy - Szz,   Syz + Szy},
    {Sxy - Syx,       Szx + Sxz,        Syz + Szy,        -Sxx - Syy + Szz}};
  double V[4][4];
  jacobi4(A, V);
  int kb = 0; double ev = A[0][0];
  for (int i = 1; i < 4; ++i) if (A[i][i] > ev) { ev = A[i][i]; kb = i; }
  double q0 = V[0][kb], qx = V[1][kb], qy = V[2][kb], qz = V[3][kb];
  double nrm = sqrt(q0 * q0 + qx * qx + qy * qy + qz * qz);
  if (nrm < 1e-300) { q0 = 1.0; qx = qy = qz = 0.0; nrm = 1.0; }
  q0 /= nrm; qx /= nrm; qy /= nrm; qz /= nrm;
  double R[3][3];
  R[0][0] = q0*q0 + qx*qx - qy*qy - qz*qz; R[0][1] = 2.0*(qx*qy - q0*qz); R[0][2] = 2.0*(qx*qz + q0*qy);
  R[1][0] = 2.0*(qx*qy + q0*qz); R[1][1] = q0*q0 - qx*qx + qy*qy - qz*qz; R[1][2] = 2.0*(qy*qz - q0*qx);
  R[2][0] = 2.0*(qx*qz - q0*qy); R[2][1] = 2.0*(qy*qz + q0*qx); R[2][2] = q0*q0 - qx*qx - qy*qy + qz*qz;
  for (int c = 0; c < 3; ++c)
    for (int d = 0; d < 3; ++d) T12[c * 3 + d] = R[c][d];
  for (int c = 0; c < 3; ++c)
    T12[9 + c] = rc[c] - (R[c][0] * sc[0] + R[c][1] * sc[1] + R[c][2] * sc[2]);
}

// ---------------- mask dtype detection (parallel) ----------------
__global__ void k_maskdetect(const unsigned* __restrict__ m, unsigned* __restrict__ hdr) {
  unsigned v = m[threadIdx.x];                  // 64 independent loads
  unsigned long long any = __ballot(v > 1u);    // u8 layout => some word packs >1
  if (threadIdx.x == 0) hdr[2] = any ? 1u : 0u;
}

// ---------------- pass 1: per-row / per-col 3rd-max thresholds ----------------
__global__ __launch_bounds__(256, 2) void k_thresh(
    const float* __restrict__ scores, float* __restrict__ rthrG, float* __restrict__ cthrG) {
  const int p = blockIdx.x;
  const int tid = threadIdx.x;
  __shared__ float colpart[2][NPT][3];
  __shared__ float tile[32 * 132];
  __shared__ float rpart[32][8][3];
  const float* S = scores + (size_t)p * NN2;
  const int col = tid & 127;
  const int half = tid >> 7;
  // column top-3: coalesced stream, branchless, no barriers inside
  {
    float a = NEGF, b = NEGF, c = NEGF;
    const float* base = S + (size_t)half * 64 * NPT + col;
#pragma unroll 8
    for (int it = 0; it < 64; ++it)
      top3_upd(base[it * NPT], a, b, c);
    colpart[half][col][0] = a; colpart[half][col][1] = b; colpart[half][col][2] = c;
  }
  __syncthreads();
  if (tid < NPT) {
    float a = colpart[0][tid][0], b = colpart[0][tid][1], c = colpart[0][tid][2];
    merge3(a, b, c, colpart[1][tid][0], colpart[1][tid][1], colpart[1][tid][2]);
    cthrG[p * NPT + tid] = c;
  }
  // row top-3 via 4 LDS-tiled chunks of 32 rows
  for (int ch = 0; ch < 4; ++ch) {
    const int cb = ch << 5;
    {
      const float* gsrc = S + (size_t)(cb + half * 16) * NPT + col;
      float* ldst = tile + (half * 16) * 132 + col;
#pragma unroll
      for (int i = 0; i < 16; ++i)
        ldst[i * 132] = gsrc[i * NPT];
    }
    __syncthreads();
    {
      const int rl = tid >> 3, o = tid & 7;
      float a = NEGF, b = NEGF, c = NEGF;
      const float* tr = tile + rl * 132 + o * 16;
#pragma unroll
      for (int k = 0; k < 16; ++k) top3_upd(tr[k], a, b, c);
      rpart[rl][o][0] = a; rpart[rl][o][1] = b; rpart[rl][o][2] = c;
    }
    __syncthreads();
    if (tid < 32) {
      float a = rpart[tid][0][0], b = rpart[tid][0][1], c = rpart[tid][0][2];
#pragma unroll
      for (int o = 1; o < 8; ++o)
        merge3(a, b, c, rpart[tid][o][0], rpart[tid][o][1], rpart[tid][o][2]);
      rthrG[p * NPT + cb + tid] = c;
    }
    __syncthreads();
  }
}

// ---------------- pass 2: corr detection + stats + candidate emission ----------------
__global__ __launch_bounds__(256, 4) void k_scan(
    const float* __restrict__ scores, const float* __restrict__ refp,
    const float* __restrict__ srcp, const void* __restrict__ mref,
    const void* __restrict__ msrc, const float* __restrict__ rthrG,
    const float* __restrict__ cthrG, unsigned* __restrict__ hist,
    unsigned* __restrict__ hdr, double* __restrict__ stats,
    unsigned long long* __restrict__ cand) {
  const int p = blockIdx.x;
  const int tid = threadIdx.x;
  const int lane = tid & 63;
  __shared__ float lrthr[NPT];
  __shared__ float lref[NPT * 3], lsrc[NPT * 3];
  __shared__ unsigned char lmr[NPT];
  __shared__ unsigned lcnt, sbase;
  __shared__ unsigned lij[MAXCORR_PB];
  __shared__ float lv[MAXCORR_PB];
  __shared__ double red[4][17];
  const unsigned maskU8 = hdr[2];
  if (tid == 0) lcnt = 0;
  for (int t = tid; t < NPT * 3; t += 256) {
    lref[t] = refp[p * NPT * 3 + t];
    lsrc[t] = srcp[p * NPT * 3 + t];
  }
  if (tid < NPT) {
    lrthr[tid] = rthrG[p * NPT + tid];
    lmr[tid] = maskU8 ? (((const unsigned char*)mref)[p * NPT + tid] != 0)
                      : (((const int*)mref)[p * NPT + tid] != 0);
  }
  const int col = tid & 127;
  const int half = tid >> 7;
  const float cth = cthrG[p * NPT + col];
  const bool msj = maskU8 ? (((const unsigned char*)msrc)[p * NPT + col] != 0)
                          : (((const int*)msrc)[p * NPT + col] != 0);
  __syncthreads();
  // pure f32 streaming scan: zero barriers, zero global atomics
  const float* S = scores + (size_t)p * NN2 + (size_t)half * 64 * NPT + col;
#pragma unroll 4
  for (int it = 0; it < 64; ++it) {
    float v = S[it * NPT];
    int i = half * 64 + it;
    if (msj && v >= cth && v >= lrthr[i] && lmr[i] && (expf(v) > THRESH)) {
      unsigned pos = atomicAdd(&lcnt, 1u);
      if (pos < MAXCORR_PB) {
        lij[pos] = (unsigned)((i << 8) | col);
        lv[pos] = v;
      }
    }
  }
  __syncthreads();
  unsigned cnt = lcnt;
  if (cnt > MAXCORR_PB) cnt = MAXCORR_PB;
  if (tid == 0) sbase = atomicAdd(&hdr[0], cnt);   // ONE global atomic per block
  __syncthreads();
  const unsigned base = sbase;
  // doubles only over the <=384 collected corrs
  double tot = 0, sr0 = 0, sr1 = 0, sr2 = 0, ss0 = 0, ss1 = 0, ss2 = 0;
  double m00 = 0, m01 = 0, m02 = 0, m10 = 0, m11 = 0, m12 = 0, m20 = 0, m21 = 0, m22 = 0;
  for (unsigned t = tid; t < cnt; t += 256) {
    unsigned ij = lij[t];
    float v = lv[t];
    int i = ij >> 8, j = ij & 255;
    double w = (double)expf(v);
    double rx = lref[i * 3], ry = lref[i * 3 + 1], rz = lref[i * 3 + 2];
    double sx = lsrc[j * 3], sy = lsrc[j * 3 + 1], sz = lsrc[j * 3 + 2];
    tot += w;
    sr0 += w * rx; sr1 += w * ry; sr2 += w * rz;
    ss0 += w * sx; ss1 += w * sy; ss2 += w * sz;
    double wsx = w * sx, wsy = w * sy, wsz = w * sz;
    m00 += wsx * rx; m01 += wsx * ry; m02 += wsx * rz;
    m10 += wsy * rx; m11 += wsy * ry; m12 += wsy * rz;
    m20 += wsz * rx; m21 += wsz * ry; m22 += wsz * rz;
    // candidate emission
    unsigned bb = __float_as_uint(v);
    unsigned enc = (bb & 0x80000000u) ? ~bb : (bb | 0x80000000u);
    unsigned pos = base + t;
    if (pos < CAND_CAP) {
      cand[pos] = (((unsigned long long)(~enc)) << 32) |
                  (unsigned long long)(unsigned)(p * NN2 + i * NPT + j);
      atomicAdd(&hist[enc >> 16], 1u);
    }
  }
  double vals[17] = {tot, sr0, sr1, sr2, ss0, ss1, ss2,
                     m00, m01, m02, m10, m11, m12, m20, m21, m22, (double)cnt};
#pragma unroll
  for (int k = 0; k < 17; ++k) {
    double x = vals[k];
    for (int o = 32; o; o >>= 1) x += __shfl_down(x, o, 64);
    if (lane == 0) red[tid >> 6][k] = x;
  }
  __syncthreads();
  if (tid == 0) {
    for (int k = 0; k < 17; ++k)
      stats[p * 20 + k] = red[0][k] + red[1][k] + red[2][k] + red[3][k];
  }
}

// ---------------- histogram cutoff ----------------
__global__ __launch_bounds__(1024) void k_cutoff(const unsigned* __restrict__ hist,
                                                 unsigned* __restrict__ hdr) {
  __shared__ unsigned ss[1024];
  const int tid = threadIdx.x;
  unsigned s = 0;
  const uint4* h4 = (const uint4*)hist + tid * 16;
#pragma unroll
  for (int q = 0; q < 16; ++q) {
    uint4 h = h4[q];
    s += h.x + h.y + h.z + h.w;
  }
  ss[tid] = s;
  __syncthreads();
  for (int off = 1; off < 1024; off <<= 1) {
    unsigned v = ss[tid];
    unsigned add = (tid + off < 1024) ? ss[tid + off] : 0u;
    __syncthreads();
    ss[tid] = v + add;
    __syncthreads();
  }
  unsigned after = (tid < 1023) ? ss[tid + 1] : 0u;
  if (after < MAXC && after + s >= MAXC) {
    unsigned acc = after;
    for (int b = tid * 64 + 63; b >= tid * 64; --b) {
      acc += hist[b];
      if (acc >= MAXC) { hdr[3] = (unsigned)b; break; }
    }
  }
}

// ---------------- compact above-cutoff candidates ----------------
__global__ __launch_bounds__(256) void k_compact(const unsigned long long* __restrict__ cand,
                                                 unsigned* __restrict__ hdr,
                                                 unsigned long long* __restrict__ sel) {
  const unsigned idx = blockIdx.x * 256 + threadIdx.x;
  const int lane = threadIdx.x & 63;
  const unsigned cc = hdr[0] < CAND_CAP ? hdr[0] : CAND_CAP;
  const unsigned cut = hdr[3];
  bool take = false;
  unsigned long long key = 0;
  if (idx < cc) {
    key = cand[idx];
    unsigned enc = ~(unsigned)(key >> 32);
    take = (enc >> 16) >= cut;
  }
  unsigned long long mb = __ballot(take);
  if (mb) {
    int leader = __ffsll((unsigned long long)mb) - 1;
    unsigned base = 0;
    if (lane == leader) base = atomicAdd(&hdr[1], (unsigned)__popcll(mb));
    base = __shfl(base, leader, 64);
    if (take) {
      unsigned pos = base + (unsigned)__popcll(mb & ((1ull << lane) - 1ull));
      if (pos < SEL_CAP) sel[pos] = key;
    }
  }
}

// ---------------- sort (LDS bitonic) + write outputs/pool ----------------
__global__ __launch_bounds__(1024) void k_sortout(
    unsigned long long* __restrict__ sel, const unsigned* __restrict__ hdr,
    const float* __restrict__ scores, const float* __restrict__ refp,
    const float* __restrict__ srcp, float* __restrict__ pool, float* __restrict__ out) {
  __shared__ unsigned long long ls[4096];
  const int tid = threadIdx.x;
  unsigned sc = hdr[1];
  if (sc > SEL_CAP) sc = SEL_CAP;
  unsigned n2 = 2048;
  while (n2 < sc) n2 <<= 1;
  const bool uselds = (n2 <= 4096);
  if (uselds) {
    for (unsigned t = tid; t < n2; t += 1024)
      ls[t] = (t < sc) ? sel[t] : 0xFFFFFFFFFFFFFFFFull;
    __syncthreads();
    for (unsigned k = 2; k <= n2; k <<= 1) {
      for (unsigned j = k >> 1; j; j >>= 1) {
        for (unsigned t = tid; t < n2; t += 1024) {
          unsigned ixj = t ^ j;
          if (ixj > t) {
            unsigned long long A = ls[t], B = ls[ixj];
            bool up = ((t & k) == 0);
            if (up ? (A > B) : (A < B)) { ls[t] = B; ls[ixj] = A; }
          }
        }
        __syncthreads();
      }
    }
  } else {
    for (unsigned t = tid; t < n2; t += 1024)
      if (t >= sc) sel[t] = 0xFFFFFFFFFFFFFFFFull;
    __syncthreads();
    for (unsigned k = 2; k <= n2; k <<= 1) {
      for (unsigned j = k >> 1; j; j >>= 1) {
        for (unsigned t = tid; t < n2; t += 1024) {
          unsigned ixj = t ^ j;
          if (ixj > t) {
            unsigned long long A = sel[t], B = sel[ixj];
            bool up = ((t & k) == 0);
            if (up ? (A > B) : (A < B)) { sel[t] = B; sel[ixj] = A; }
          }
        }
        __syncthreads();
      }
    }
  }
  for (int mm = tid; mm < MAXC; mm += 1024) {
    unsigned flat; float score; bool real;
    if ((unsigned)mm < sc) {
      unsigned long long key = uselds ? ls[mm] : sel[mm];
      flat = (unsigned)(key & 0xFFFFFFFFull);
      score = expf(scores[flat]);
      real = true;
    } else {
      flat = (unsigned)mm;
      score = 0.f;
      real = false;
    }
    unsigned p = flat >> 14, rem = flat & 16383u, i = rem >> 7, j = rem & 127u;
    float rx = refp[((size_t)p * NPT + i) * 3 + 0];
    float ry = refp[((size_t)p * NPT + i) * 3 + 1];
    float rz = refp[((size_t)p * NPT + i) * 3 + 2];
    float sx = srcp[((size_t)p * NPT + j) * 3 + 0];
    float sy = srcp[((size_t)p * NPT + j) * 3 + 1];
    float sz = srcp[((size_t)p * NPT + j) * 3 + 2];
    out[mm * 3 + 0] = rx; out[mm * 3 + 1] = ry; out[mm * 3 + 2] = rz;
    out[4500 + mm * 3 + 0] = sx; out[4500 + mm * 3 + 1] = sy; out[4500 + mm * 3 + 2] = sz;
    out[9000 + mm] = score;
    pool[mm * 3 + 0] = rx; pool[mm * 3 + 1] = ry; pool[mm * 3 + 2] = rz;
    pool[4500 + mm * 3 + 0] = sx; pool[4500 + mm * 3 + 1] = sy; pool[4500 + mm * 3 + 2] = sz;
    float pad = real ? 0.f : 1e6f;
    pool[9000 + mm * 3 + 0] = sx + pad;
    pool[9000 + mm * 3 + 1] = sy + pad;
    pool[9000 + mm * 3 + 2] = sz + pad;
    pool[13500 + mm] = score;
  }
}

// ---------------- per-proposal transforms ----------------
__global__ __launch_bounds__(64, 1) void k_transforms(const double* __restrict__ stats,
                                                      double* __restrict__ trans) {
  int p = blockIdx.x * 64 + threadIdx.x;
  if (p >= PP) return;
  const double* st = stats + p * 20;
  double sr[3] = {st[1], st[2], st[3]};
  double ss[3] = {st[4], st[5], st[6]};
  double m9[9];
  for (int k = 0; k < 9; ++k) m9[k] = st[7 + k];
  kabsch_from_sums(st[0], sr, ss, m9, trans + p * 12);
}

// ---------------- inlier counting per proposal ----------------
__global__ __launch_bounds__(256) void k_eval(const double* __restrict__ trans,
                                              const double* __restrict__ stats,
                                              const float* __restrict__ pool,
                                              int* __restrict__ icount) {
  const int p = blockIdx.x, tid = threadIdx.x, lane = tid & 63;
  __shared__ int redc[4];
  const double* T = trans + p * 12;
  double R00 = T[0], R01 = T[1], R02 = T[2], R10 = T[3], R11 = T[4], R12 = T[5];
  double R20 = T[6], R21 = T[7], R22 = T[8], t0 = T[9], t1 = T[10], t2 = T[11];
  const float* pr = pool;
  const float* pe = pool + 9000;
  int cnt = 0;
  for (int mm = tid; mm < MAXC; mm += 256) {
    double ex = pe[mm * 3], ey = pe[mm * 3 + 1], ez = pe[mm * 3 + 2];
    double ax = R00 * ex + R01 * ey + R02 * ez + t0;
    double ay = R10 * ex + R11 * ey + R12 * ez + t1;
    double az = R20 * ex + R21 * ey + R22 * ez + t2;
    double dx = pr[mm * 3] - ax, dy = pr[mm * 3 + 1] - ay, dz = pr[mm * 3 + 2] - az;
    if (dx * dx + dy * dy + dz * dz < RRD) ++cnt;
  }
  for (int o = 32; o; o >>= 1) cnt += __shfl_down(cnt, o, 64);
  if (lane == 0) redc[tid >> 6] = cnt;
  __syncthreads();
  if (tid == 0) {
    int tc = redc[0] + redc[1] + redc[2] + redc[3];
    icount[p] = (stats[p * 20 + 16] >= 3.0) ? tc : -1;
  }
}

// ---------------- argmax + iterative refinement ----------------
__global__ __launch_bounds__(256, 1) void k_refine(const double* __restrict__ trans,
                                                   const int* __restrict__ icount,
                                                   const float* __restrict__ pool,
                                                   float* __restrict__ out) {
  const int tid = threadIdx.x, lane = tid & 63;
  __shared__ int rc_[256], ri_[256];
  __shared__ double red[4][16];
  __shared__ double T[12];
  int bc = -2147483647, bi = 0;
  for (int idx = tid; idx < PP; idx += 256) {
    int c = icount[idx];
    if (c > bc) { bc = c; bi = idx; }
  }
  rc_[tid] = bc; ri_[tid] = bi;
  __syncthreads();
  for (int s = 128; s; s >>= 1) {
    if (tid < s) {
      int c2 = rc_[tid + s], i2 = ri_[tid + s];
      if (c2 > rc_[tid] || (c2 == rc_[tid] && i2 < ri_[tid])) { rc_[tid] = c2; ri_[tid] = i2; }
    }
    __syncthreads();
  }
  if (tid == 0) {
    int best = ri_[0];
    for (int k = 0; k < 12; ++k) T[k] = trans[best * 12 + k];
  }
  __syncthreads();
  const float* pr = pool;
  const float* ps = pool + 4500;
  const float* pe = pool + 9000;
  const float* pw = pool + 13500;
  for (int iter = 0; iter < 5; ++iter) {
    double R00 = T[0], R01 = T[1], R02 = T[2], R10 = T[3], R11 = T[4], R12 = T[5];
    double R20 = T[6], R21 = T[7], R22 = T[8], t0 = T[9], t1 = T[10], t2 = T[11];
    double tot = 0, sr0 = 0, sr1 = 0, sr2 = 0, ss0 = 0, ss1 = 0, ss2 = 0;
    double m00 = 0, m01 = 0, m02 = 0, m10 = 0, m11 = 0, m12 = 0, m20 = 0, m21 = 0, m22 = 0;
    for (int mm = tid; mm < MAXC; mm += 256) {
      double ex = pe[mm * 3], ey = pe[mm * 3 + 1], ez = pe[mm * 3 + 2];
      double ax = R00 * ex + R01 * ey + R02 * ez + t0;
      double ay = R10 * ex + R11 * ey + R12 * ez + t1;
      double az = R20 * ex + R21 * ey + R22 * ez + t2;
      double rx = pr[mm * 3], ry = pr[mm * 3 + 1], rz = pr[mm * 3 + 2];
      double dx = rx - ax, dy = ry - ay, dz = rz - az;
      if (dx * dx + dy * dy + dz * dz < RRD) {
        double w = (double)pw[mm];
        double sx = ps[mm * 3], sy = ps[mm * 3 + 1], sz = ps[mm * 3 + 2];
        tot += w;
        sr0 += w * rx; sr1 += w * ry; sr2 += w * rz;
        ss0 += w * sx; ss1 += w * sy; ss2 += w * sz;
        double wsx = w * sx, wsy = w * sy, wsz = w * sz;
        m00 += wsx * rx; m01 += wsx * ry; m02 += wsx * rz;
        m10 += wsy * rx; m11 += wsy * ry; m12 += wsy * rz;
        m20 += wsz * rx; m21 += wsz * ry; m22 += wsz * rz;
      }
    }
    double vals[16] = {tot, sr0, sr1, sr2, ss0, ss1, ss2,
                       m00, m01, m02, m10, m11, m12, m20, m21, m22};
#pragma unroll
    for (int k = 0; k < 16; ++k) {
      double x = vals[k];
      for (int o = 32; o; o >>= 1) x += __shfl_down(x, o, 64);
      if (lane == 0) red[tid >> 6][k] = x;
    }
    __syncthreads();
    if (tid == 0) {
      double s16[16];
      for (int k = 0; k < 16; ++k)
        s16[k] = red[0][k] + red[1][k] + red[2][k] + red[3][k];
      kabsch_from_sums(s16[0], s16 + 1, s16 + 4, s16 + 7, T);
    }
    __syncthreads();
  }
  if (tid == 0) {
    out[10500 + 0]  = (float)T[0]; out[10500 + 1]  = (float)T[1];
    out[10500 + 2]  = (float)T[2]; out[10500 + 3]  = (float)T[9];
    out[10500 + 4]  = (float)T[3]; out[10500 + 5]  = (float)T[4];
    out[10500 + 6]  = (float)T[5]; out[10500 + 7]  = (float)T[10];
    out[10500 + 8]  = (float)T[6]; out[10500 + 9]  = (float)T[7];
    out[10500 + 10] = (float)T[8]; out[10500 + 11] = (float)T[11];
    out[10500 + 12] = 0.f; out[10500 + 13] = 0.f;
    out[10500 + 14] = 0.f; out[10500 + 15] = 1.f;
  }
}

extern "C" void kernel_launch(void* const* d_in, const int* in_sizes, int n_in,
                              void* d_out, int out_size, void* d_ws, size_t ws_size,
                              hipStream_t stream) {
  const float* refp = (const float*)d_in[0];
  const float* srcp = (const float*)d_in[1];
  const void* mref = d_in[2];
  const void* msrc = d_in[3];
  const float* scores = (const float*)d_in[4];
  float* out = (float*)d_out;
  char* ws = (char*)d_ws;
  unsigned* hist = (unsigned*)(ws + OFF_HIST);
  unsigned* hdr = (unsigned*)(ws + OFF_HDR);
  double* stats = (double*)(ws + OFF_STATS);
  double* trans = (double*)(ws + OFF_TRANS);
  int* icount = (int*)(ws + OFF_ICNT);
  float* pool = (float*)(ws + OFF_POOL);
  unsigned long long* cand = (unsigned long long*)(ws + OFF_CAND);
  unsigned long long* sel = (unsigned long long*)(ws + OFF_SEL);
  float* rthrG = (float*)(ws + OFF_RTHR);
  float* cthrG = (float*)(ws + OFF_CTHR);

  (void)hipMemsetAsync(ws, 0, OFF_STATS, stream);  // hist + hdr
  k_maskdetect<<<1, 64, 0, stream>>>((const unsigned*)mref, hdr);
  k_thresh<<<PP, 256, 0, stream>>>(scores, rthrG, cthrG);
  k_scan<<<PP, 256, 0, stream>>>(scores, refp, srcp, mref, msrc, rthrG, cthrG,
                                 hist, hdr, stats, cand);
  k_cutoff<<<1, 1024, 0, stream>>>(hist, hdr);
  k_compact<<<CAND_CAP / 256, 256, 0, stream>>>(cand, hdr, sel);
  k_sortout<<<1, 1024, 0, stream>>>(sel, hdr, scores, refp, srcp, pool, out);
  k_transforms<<<16, 64, 0, stream>>>(stats, trans);
  k_eval<<<PP, 256, 0, stream>>>(trans, stats, pool, icount);
  k_refine<<<1, 256, 0, stream>>>(trans, icount, pool, out);
}

// Round 4
// 567.801 us; speedup vs baseline: 3.8091x; 1.0438x over previous
//
#include <hip/hip_runtime.h>
#include <math.h>

#define PP    1024
#define NPT   128
#define NN2   16384        // NPT*NPT
#define THRESH 0.05f
#define MAXC  1500
#define EPSD  1e-5
#define RRD   (0.1*0.1)
#define CAND_CAP 393216u
#define SEL_CAP  65536u
#define NEGF  -3.0e38f
#define MAXCORR_PB 384     // hard cap: mutual ⊆ row-top3 => <=3*128 per proposal

// ---- workspace byte offsets ----
#define OFF_HIST  0          // uint32[65536]                 -> 262144
#define OFF_HDR   262144     // uint32[16]: 0=candCount 1=selCount 2=maskU8 3=cutoff
#define OFF_STATS 262208     // double[1024*20]               -> +163840 = 426048
#define OFF_TRANS 426048     // double[1024*12]               -> +98304  = 524352
#define OFF_ICNT  524352     // int[1024]                     -> +4096   = 528448
#define OFF_POOL  528448     // float[1500*10]                -> +60000  = 588448
#define OFF_CAND  588448     // u64[CAND_CAP]                 -> +3145728= 3734176
#define OFF_SEL   3734176    // u64[SEL_CAP]                  -> +524288 = 4258464

// ---------------- branchless top-3 helpers ----------------
__device__ inline void top3_upd(float v, float& a, float& b, float& c) {
  float m1 = fminf(a, v);
  a = fmaxf(a, v);
  float m2 = fminf(b, m1);
  b = fmaxf(b, m1);
  c = fmaxf(c, m2);
}
__device__ inline void merge3(float& a, float& b, float& c, float x0, float x1, float x2) {
  float z0 = fmaxf(a, x0);
  float z1 = fmaxf(fminf(a, x0), fmaxf(b, x1));
  float z2 = fmaxf(fmaxf(c, x2), fmaxf(fminf(b, x0), fminf(a, x1)));
  a = z0; b = z1; c = z2;
}

// ---------------- quaternion Kabsch (Horn 1987) ----------------
__device__ inline void jacobi4(double A[4][4], double V[4][4]) {
  for (int i = 0; i < 4; ++i)
    for (int j = 0; j < 4; ++j) V[i][j] = (i == j) ? 1.0 : 0.0;
  const int PI_[6] = {0, 0, 0, 1, 1, 2};
  const int QI_[6] = {1, 2, 3, 2, 3, 3};
  for (int sweep = 0; sweep < 30; ++sweep) {
    double off = fabs(A[0][1]) + fabs(A[0][2]) + fabs(A[0][3]) +
                 fabs(A[1][2]) + fabs(A[1][3]) + fabs(A[2][3]);
    double dia = fabs(A[0][0]) + fabs(A[1][1]) + fabs(A[2][2]) + fabs(A[3][3]);
    if (off <= 1e-15 * (dia + 1e-300)) break;
#pragma unroll
    for (int r = 0; r < 6; ++r) {
      int p = PI_[r], q = QI_[r];
      double apq = A[p][q];
      if (fabs(apq) <= 1e-18 * (fabs(A[p][p]) + fabs(A[q][q]) + 1e-300)) continue;
      double theta = (A[q][q] - A[p][p]) / (2.0 * apq);
      double t = ((theta >= 0.0) ? 1.0 : -1.0) / (fabs(theta) + sqrt(1.0 + theta * theta));
      double c = 1.0 / sqrt(1.0 + t * t);
      double s = t * c;
#pragma unroll
      for (int k = 0; k < 4; ++k) {
        double akp = A[k][p], akq = A[k][q];
        A[k][p] = c * akp - s * akq;
        A[k][q] = s * akp + c * akq;
      }
#pragma unroll
      for (int k = 0; k < 4; ++k) {
        double apk = A[p][k], aqk = A[q][k];
        A[p][k] = c * apk - s * aqk;
        A[q][k] = s * apk + c * aqk;
      }
#pragma unroll
      for (int k = 0; k < 4; ++k) {
        double vkp = V[k][p], vkq = V[k][q];
        V[k][p] = c * vkp - s * vkq;
        V[k][q] = s * vkp + c * vkq;
      }
    }
  }
}

__device__ inline void kabsch_from_sums(double tot, const double* sr, const double* ss,
                                        const double* m9, double* T12) {
  double den = tot + EPSD;
  double rc[3], sc[3];
  for (int c = 0; c < 3; ++c) { rc[c] = sr[c] / den; sc[c] = ss[c] / den; }
  double sb = tot / den;
  double H[3][3];
  for (int c = 0; c < 3; ++c)
    for (int d = 0; d < 3; ++d)
      H[c][d] = m9[c * 3 + d] / den - (2.0 - sb) * sc[c] * rc[d];
  if (tot < EPSD) {
    H[0][0] = 3.0; H[0][1] = 0.0; H[0][2] = 0.0;
    H[1][0] = 0.0; H[1][1] = 2.0; H[1][2] = 0.0;
    H[2][0] = 0.0; H[2][1] = 0.0; H[2][2] = 1.0;
  }
  double Sxx = H[0][0], Sxy = H[0][1], Sxz = H[0][2];
  double Syx = H[1][0], Syy = H[1][1], Syz = H[1][2];
  double Szx = H[2][0], Szy = H[2][1], Szz = H[2][2];
  double A[4][4] = {
    {Sxx + Syy + Szz, Syz - Szy,        Szx - Sxz,         Sxy - Syx},
    {Syz - Szy,       Sxx - Syy - Szz,  Sxy + Syx,         Szx + Sxz},
    {Szx - Sxz,       Sxy + Syx,       -Sxx + Syy - Szz,   Syz + Szy},
    {Sxy - Syx,       Szx + Sxz,        Syz + Szy,        -Sxx - Syy + Szz}};
  double V[4][4];
  jacobi4(A, V);
  int kb = 0; double ev = A[0][0];
  for (int i = 1; i < 4; ++i) if (A[i][i] > ev) { ev = A[i][i]; kb = i; }
  double q0 = V[0][kb], qx = V[1][kb], qy = V[2][kb], qz = V[3][kb];
  double nrm = sqrt(q0 * q0 + qx * qx + qy * qy + qz * qz);
  if (nrm < 1e-300) { q0 = 1.0; qx = qy = qz = 0.0; nrm = 1.0; }
  q0 /= nrm; qx /= nrm; qy /= nrm; qz /= nrm;
  double R[3][3];
  R[0][0] = q0*q0 + qx*qx - qy*qy - qz*qz; R[0][1] = 2.0*(qx*qy - q0*qz); R[0][2] = 2.0*(qx*qz + q0*qy);
  R[1][0] = 2.0*(qx*qy + q0*qz); R[1][1] = q0*q0 - qx*qx + qy*qy - qz*qz; R[1][2] = 2.0*(qy*qz - q0*qx);
  R[2][0] = 2.0*(qx*qz - q0*qy); R[2][1] = 2.0*(qy*qz + q0*qx); R[2][2] = q0*q0 - qx*qx - qy*qy + qz*qz;
  for (int c = 0; c < 3; ++c)
    for (int d = 0; d < 3; ++d) T12[c * 3 + d] = R[c][d];
  for (int c = 0; c < 3; ++c)
    T12[9 + c] = rc[c] - (R[c][0] * sc[0] + R[c][1] * sc[1] + R[c][2] * sc[2]);
}

// ---------------- mask dtype detection (parallel) ----------------
__global__ void k_maskdetect(const unsigned* __restrict__ m, unsigned* __restrict__ hdr) {
  unsigned v = m[threadIdx.x];
  unsigned long long any = __ballot(v > 1u);
  if (threadIdx.x == 0) hdr[2] = any ? 1u : 0u;
}

// ---------------- fused: stage tile once, thresholds + scan from LDS ----------------
__global__ __launch_bounds__(256, 2) void k_fused(
    const float* __restrict__ scores, const float* __restrict__ refp,
    const float* __restrict__ srcp, const void* __restrict__ mref,
    const void* __restrict__ msrc, unsigned* __restrict__ hist,
    unsigned* __restrict__ hdr, double* __restrict__ stats,
    unsigned long long* __restrict__ cand) {
  const int p = blockIdx.x;
  const int tid = threadIdx.x;
  const int lane = tid & 63;
  __shared__ float tile[128 * 132];        // padded: word (132r+c), conflict-safe
  __shared__ float rthr[NPT], cthr[NPT];
  __shared__ float colpart[2][NPT][3];
  __shared__ float lref[NPT * 3], lsrc[NPT * 3];
  __shared__ unsigned char lmr[NPT];
  __shared__ unsigned lcnt, sbase;
  __shared__ unsigned lij[MAXCORR_PB];
  __shared__ float lv[MAXCORR_PB];
  __shared__ double red[4][17];
  const unsigned maskU8 = hdr[2];
  if (tid == 0) lcnt = 0;
  // ---- stage the whole 128x128 tile: 16 independent coalesced float4 loads ----
  {
    const float4* S4 = (const float4*)(scores + (size_t)p * NN2);
    float4 vv[16];
#pragma unroll
    for (int s = 0; s < 16; ++s)
      vv[s] = S4[s * 256 + tid];           // 1 KB/wave/instr, fully coalesced
#pragma unroll
    for (int s = 0; s < 16; ++s) {
      int flat = (s * 256 + tid) * 4;      // float index
      int r = flat >> 7, c = flat & 127;
      *(float4*)&tile[r * 132 + c] = vv[s];
    }
  }
  for (int t = tid; t < NPT * 3; t += 256) {
    lref[t] = refp[p * NPT * 3 + t];
    lsrc[t] = srcp[p * NPT * 3 + t];
  }
  if (tid < NPT)
    lmr[tid] = maskU8 ? (((const unsigned char*)mref)[p * NPT + tid] != 0)
                      : (((const int*)mref)[p * NPT + tid] != 0);
  const int col = tid & 127;
  const int half = tid >> 7;
  const bool msj = maskU8 ? (((const unsigned char*)msrc)[p * NPT + col] != 0)
                          : (((const int*)msrc)[p * NPT + col] != 0);
  __syncthreads();
  // ---- row top-3: 8 lanes/row, b128 reads, shuffle-xor butterfly merge ----
  for (int rb = 0; rb < 4; ++rb) {
    int r = rb * 32 + (tid >> 3);
    int o = tid & 7;
    float a = NEGF, b = NEGF, c = NEGF;
    const float4* tr = (const float4*)&tile[r * 132 + o * 16];
#pragma unroll
    for (int k = 0; k < 4; ++k) {
      float4 q = tr[k];
      top3_upd(q.x, a, b, c); top3_upd(q.y, a, b, c);
      top3_upd(q.z, a, b, c); top3_upd(q.w, a, b, c);
    }
#pragma unroll
    for (int m = 1; m < 8; m <<= 1) {
      float pa = __shfl_xor(a, m, 64), pb = __shfl_xor(b, m, 64), pc = __shfl_xor(c, m, 64);
      merge3(a, b, c, pa, pb, pc);
    }
    if (o == 0) rthr[r] = c;
  }
  // ---- col top-3: consecutive-lane (conflict-free) LDS reads ----
  {
    float a = NEGF, b = NEGF, c = NEGF;
    const float* tc = tile + (half * 64) * 132 + col;
#pragma unroll 8
    for (int r = 0; r < 64; ++r)
      top3_upd(tc[r * 132], a, b, c);
    colpart[half][col][0] = a; colpart[half][col][1] = b; colpart[half][col][2] = c;
  }
  __syncthreads();
  if (tid < NPT) {
    float a = colpart[0][tid][0], b = colpart[0][tid][1], c = colpart[0][tid][2];
    merge3(a, b, c, colpart[1][tid][0], colpart[1][tid][1], colpart[1][tid][2]);
    cthr[tid] = c;
  }
  __syncthreads();
  // ---- corr scan from LDS ----
  {
    const float cth = cthr[col];
    const float* tc = tile + (half * 64) * 132 + col;
#pragma unroll 4
    for (int it = 0; it < 64; ++it) {
      float v = tc[it * 132];
      int i = half * 64 + it;
      if (msj && v >= cth && v >= rthr[i] && lmr[i] && (expf(v) > THRESH)) {
        unsigned pos = atomicAdd(&lcnt, 1u);
        if (pos < MAXCORR_PB) {
          lij[pos] = (unsigned)((i << 8) | col);
          lv[pos] = v;
        }
      }
    }
  }
  __syncthreads();
  unsigned cnt = lcnt;
  if (cnt > MAXCORR_PB) cnt = MAXCORR_PB;
  if (tid == 0) sbase = atomicAdd(&hdr[0], cnt);   // ONE global atomic per block
  __syncthreads();
  const unsigned base = sbase;
  // ---- doubles only over the collected corrs ----
  double tot = 0, sr0 = 0, sr1 = 0, sr2 = 0, ss0 = 0, ss1 = 0, ss2 = 0;
  double m00 = 0, m01 = 0, m02 = 0, m10 = 0, m11 = 0, m12 = 0, m20 = 0, m21 = 0, m22 = 0;
  for (unsigned t = tid; t < cnt; t += 256) {
    unsigned ij = lij[t];
    float v = lv[t];
    int i = ij >> 8, j = ij & 255;
    double w = (double)expf(v);
    double rx = lref[i * 3], ry = lref[i * 3 + 1], rz = lref[i * 3 + 2];
    double sx = lsrc[j * 3], sy = lsrc[j * 3 + 1], sz = lsrc[j * 3 + 2];
    tot += w;
    sr0 += w * rx; sr1 += w * ry; sr2 += w * rz;
    ss0 += w * sx; ss1 += w * sy; ss2 += w * sz;
    double wsx = w * sx, wsy = w * sy, wsz = w * sz;
    m00 += wsx * rx; m01 += wsx * ry; m02 += wsx * rz;
    m10 += wsy * rx; m11 += wsy * ry; m12 += wsy * rz;
    m20 += wsz * rx; m21 += wsz * ry; m22 += wsz * rz;
    unsigned bb = __float_as_uint(v);
    unsigned enc = (bb & 0x80000000u) ? ~bb : (bb | 0x80000000u);
    unsigned pos = base + t;
    if (pos < CAND_CAP) {
      cand[pos] = (((unsigned long long)(~enc)) << 32) |
                  (unsigned long long)(unsigned)(p * NN2 + i * NPT + j);
      atomicAdd(&hist[enc >> 16], 1u);
    }
  }
  double vals[17] = {tot, sr0, sr1, sr2, ss0, ss1, ss2,
                     m00, m01, m02, m10, m11, m12, m20, m21, m22, (double)cnt};
#pragma unroll
  for (int k = 0; k < 17; ++k) {
    double x = vals[k];
    for (int o = 32; o; o >>= 1) x += __shfl_down(x, o, 64);
    if (lane == 0) red[tid >> 6][k] = x;
  }
  __syncthreads();
  if (tid == 0) {
    for (int k = 0; k < 17; ++k)
      stats[p * 20 + k] = red[0][k] + red[1][k] + red[2][k] + red[3][k];
  }
}

// ---------------- histogram cutoff ----------------
__global__ __launch_bounds__(1024) void k_cutoff(const unsigned* __restrict__ hist,
                                                 unsigned* __restrict__ hdr) {
  __shared__ unsigned ss[1024];
  const int tid = threadIdx.x;
  unsigned s = 0;
  const uint4* h4 = (const uint4*)hist + tid * 16;
#pragma unroll
  for (int q = 0; q < 16; ++q) {
    uint4 h = h4[q];
    s += h.x + h.y + h.z + h.w;
  }
  ss[tid] = s;
  __syncthreads();
  for (int off = 1; off < 1024; off <<= 1) {
    unsigned v = ss[tid];
    unsigned add = (tid + off < 1024) ? ss[tid + off] : 0u;
    __syncthreads();
    ss[tid] = v + add;
    __syncthreads();
  }
  unsigned after = (tid < 1023) ? ss[tid + 1] : 0u;
  if (after < MAXC && after + s >= MAXC) {
    unsigned acc = after;
    for (int b = tid * 64 + 63; b >= tid * 64; --b) {
      acc += hist[b];
      if (acc >= MAXC) { hdr[3] = (unsigned)b; break; }
    }
  }
}

// ---------------- compact above-cutoff candidates ----------------
__global__ __launch_bounds__(256) void k_compact(const unsigned long long* __restrict__ cand,
                                                 unsigned* __restrict__ hdr,
                                                 unsigned long long* __restrict__ sel) {
  const unsigned idx = blockIdx.x * 256 + threadIdx.x;
  const int lane = threadIdx.x & 63;
  const unsigned cc = hdr[0] < CAND_CAP ? hdr[0] : CAND_CAP;
  const unsigned cut = hdr[3];
  bool take = false;
  unsigned long long key = 0;
  if (idx < cc) {
    key = cand[idx];
    unsigned enc = ~(unsigned)(key >> 32);
    take = (enc >> 16) >= cut;
  }
  unsigned long long mb = __ballot(take);
  if (mb) {
    int leader = __ffsll((unsigned long long)mb) - 1;
    unsigned base = 0;
    if (lane == leader) base = atomicAdd(&hdr[1], (unsigned)__popcll(mb));
    base = __shfl(base, leader, 64);
    if (take) {
      unsigned pos = base + (unsigned)__popcll(mb & ((1ull << lane) - 1ull));
      if (pos < SEL_CAP) sel[pos] = key;
    }
  }
}

// ---------------- sort (LDS bitonic) + write outputs/pool ----------------
__global__ __launch_bounds__(1024) void k_sortout(
    unsigned long long* __restrict__ sel, const unsigned* __restrict__ hdr,
    const float* __restrict__ scores, const float* __restrict__ refp,
    const float* __restrict__ srcp, float* __restrict__ pool, float* __restrict__ out) {
  __shared__ unsigned long long ls[4096];
  const int tid = threadIdx.x;
  unsigned sc = hdr[1];
  if (sc > SEL_CAP) sc = SEL_CAP;
  unsigned n2 = 2048;
  while (n2 < sc) n2 <<= 1;
  const bool uselds = (n2 <= 4096);
  if (uselds) {
    for (unsigned t = tid; t < n2; t += 1024)
      ls[t] = (t < sc) ? sel[t] : 0xFFFFFFFFFFFFFFFFull;
    __syncthreads();
    for (unsigned k = 2; k <= n2; k <<= 1) {
      for (unsigned j = k >> 1; j; j >>= 1) {
        for (unsigned t = tid; t < n2; t += 1024) {
          unsigned ixj = t ^ j;
          if (ixj > t) {
            unsigned long long A = ls[t], B = ls[ixj];
            bool up = ((t & k) == 0);
            if (up ? (A > B) : (A < B)) { ls[t] = B; ls[ixj] = A; }
          }
        }
        __syncthreads();
      }
    }
  } else {
    for (unsigned t = tid; t < n2; t += 1024)
      if (t >= sc) sel[t] = 0xFFFFFFFFFFFFFFFFull;
    __syncthreads();
    for (unsigned k = 2; k <= n2; k <<= 1) {
      for (unsigned j = k >> 1; j; j >>= 1) {
        for (unsigned t = tid; t < n2; t += 1024) {
          unsigned ixj = t ^ j;
          if (ixj > t) {
            unsigned long long A = sel[t], B = sel[ixj];
            bool up = ((t & k) == 0);
            if (up ? (A > B) : (A < B)) { sel[t] = B; sel[ixj] = A; }
          }
        }
        __syncthreads();
      }
    }
  }
  for (int mm = tid; mm < MAXC; mm += 1024) {
    unsigned flat; float score; bool real;
    if ((unsigned)mm < sc) {
      unsigned long long key = uselds ? ls[mm] : sel[mm];
      flat = (unsigned)(key & 0xFFFFFFFFull);
      score = expf(scores[flat]);
      real = true;
    } else {
      flat = (unsigned)mm;
      score = 0.f;
      real = false;
    }
    unsigned p = flat >> 14, rem = flat & 16383u, i = rem >> 7, j = rem & 127u;
    float rx = refp[((size_t)p * NPT + i) * 3 + 0];
    float ry = refp[((size_t)p * NPT + i) * 3 + 1];
    float rz = refp[((size_t)p * NPT + i) * 3 + 2];
    float sx = srcp[((size_t)p * NPT + j) * 3 + 0];
    float sy = srcp[((size_t)p * NPT + j) * 3 + 1];
    float sz = srcp[((size_t)p * NPT + j) * 3 + 2];
    out[mm * 3 + 0] = rx; out[mm * 3 + 1] = ry; out[mm * 3 + 2] = rz;
    out[4500 + mm * 3 + 0] = sx; out[4500 + mm * 3 + 1] = sy; out[4500 + mm * 3 + 2] = sz;
    out[9000 + mm] = score;
    pool[mm * 3 + 0] = rx; pool[mm * 3 + 1] = ry; pool[mm * 3 + 2] = rz;
    pool[4500 + mm * 3 + 0] = sx; pool[4500 + mm * 3 + 1] = sy; pool[4500 + mm * 3 + 2] = sz;
    float pad = real ? 0.f : 1e6f;
    pool[9000 + mm * 3 + 0] = sx + pad;
    pool[9000 + mm * 3 + 1] = sy + pad;
    pool[9000 + mm * 3 + 2] = sz + pad;
    pool[13500 + mm] = score;
  }
}

// ---------------- per-proposal transforms ----------------
__global__ __launch_bounds__(64, 1) void k_transforms(const double* __restrict__ stats,
                                                      double* __restrict__ trans) {
  int p = blockIdx.x * 64 + threadIdx.x;
  if (p >= PP) return;
  const double* st = stats + p * 20;
  double sr[3] = {st[1], st[2], st[3]};
  double ss[3] = {st[4], st[5], st[6]};
  double m9[9];
  for (int k = 0; k < 9; ++k) m9[k] = st[7 + k];
  kabsch_from_sums(st[0], sr, ss, m9, trans + p * 12);
}

// ---------------- inlier counting per proposal ----------------
__global__ __launch_bounds__(256) void k_eval(const double* __restrict__ trans,
                                              const double* __restrict__ stats,
                                              const float* __restrict__ pool,
                                              int* __restrict__ icount) {
  const int p = blockIdx.x, tid = threadIdx.x, lane = tid & 63;
  __shared__ int redc[4];
  const double* T = trans + p * 12;
  double R00 = T[0], R01 = T[1], R02 = T[2], R10 = T[3], R11 = T[4], R12 = T[5];
  double R20 = T[6], R21 = T[7], R22 = T[8], t0 = T[9], t1 = T[10], t2 = T[11];
  const float* pr = pool;
  const float* pe = pool + 9000;
  int cnt = 0;
  for (int mm = tid; mm < MAXC; mm += 256) {
    double ex = pe[mm * 3], ey = pe[mm * 3 + 1], ez = pe[mm * 3 + 2];
    double ax = R00 * ex + R01 * ey + R02 * ez + t0;
    double ay = R10 * ex + R11 * ey + R12 * ez + t1;
    double az = R20 * ex + R21 * ey + R22 * ez + t2;
    double dx = pr[mm * 3] - ax, dy = pr[mm * 3 + 1] - ay, dz = pr[mm * 3 + 2] - az;
    if (dx * dx + dy * dy + dz * dz < RRD) ++cnt;
  }
  for (int o = 32; o; o >>= 1) cnt += __shfl_down(cnt, o, 64);
  if (lane == 0) redc[tid >> 6] = cnt;
  __syncthreads();
  if (tid == 0) {
    int tc = redc[0] + redc[1] + redc[2] + redc[3];
    icount[p] = (stats[p * 20 + 16] >= 3.0) ? tc : -1;
  }
}

// ---------------- argmax + iterative refinement ----------------
__global__ __launch_bounds__(256, 1) void k_refine(const double* __restrict__ trans,
                                                   const int* __restrict__ icount,
                                                   const float* __restrict__ pool,
                                                   float* __restrict__ out) {
  const int tid = threadIdx.x, lane = tid & 63;
  __shared__ int rc_[256], ri_[256];
  __shared__ double red[4][16];
  __shared__ double T[12];
  int bc = -2147483647, bi = 0;
  for (int idx = tid; idx < PP; idx += 256) {
    int c = icount[idx];
    if (c > bc) { bc = c; bi = idx; }
  }
  rc_[tid] = bc; ri_[tid] = bi;
  __syncthreads();
  for (int s = 128; s; s >>= 1) {
    if (tid < s) {
      int c2 = rc_[tid + s], i2 = ri_[tid + s];
      if (c2 > rc_[tid] || (c2 == rc_[tid] && i2 < ri_[tid])) { rc_[tid] = c2; ri_[tid] = i2; }
    }
    __syncthreads();
  }
  if (tid == 0) {
    int best = ri_[0];
    for (int k = 0; k < 12; ++k) T[k] = trans[best * 12 + k];
  }
  __syncthreads();
  const float* pr = pool;
  const float* ps = pool + 4500;
  const float* pe = pool + 9000;
  const float* pw = pool + 13500;
  for (int iter = 0; iter < 5; ++iter) {
    double R00 = T[0], R01 = T[1], R02 = T[2], R10 = T[3], R11 = T[4], R12 = T[5];
    double R20 = T[6], R21 = T[7], R22 = T[8], t0 = T[9], t1 = T[10], t2 = T[11];
    double tot = 0, sr0 = 0, sr1 = 0, sr2 = 0, ss0 = 0, ss1 = 0, ss2 = 0;
    double m00 = 0, m01 = 0, m02 = 0, m10 = 0, m11 = 0, m12 = 0, m20 = 0, m21 = 0, m22 = 0;
    for (int mm = tid; mm < MAXC; mm += 256) {
      double ex = pe[mm * 3], ey = pe[mm * 3 + 1], ez = pe[mm * 3 + 2];
      double ax = R00 * ex + R01 * ey + R02 * ez + t0;
      double ay = R10 * ex + R11 * ey + R12 * ez + t1;
      double az = R20 * ex + R21 * ey + R22 * ez + t2;
      double rx = pr[mm * 3], ry = pr[mm * 3 + 1], rz = pr[mm * 3 + 2];
      double dx = rx - ax, dy = ry - ay, dz = rz - az;
      if (dx * dx + dy * dy + dz * dz < RRD) {
        double w = (double)pw[mm];
        double sx = ps[mm * 3], sy = ps[mm * 3 + 1], sz = ps[mm * 3 + 2];
        tot += w;
        sr0 += w * rx; sr1 += w * ry; sr2 += w * rz;
        ss0 += w * sx; ss1 += w * sy; ss2 += w * sz;
        double wsx = w * sx, wsy = w * sy, wsz = w * sz;
        m00 += wsx * rx; m01 += wsx * ry; m02 += wsx * rz;
        m10 += wsy * rx; m11 += wsy * ry; m12 += wsy * rz;
        m20 += wsz * rx; m21 += wsz * ry; m22 += wsz * rz;
      }
    }
    double vals[16] = {tot, sr0, sr1, sr2, ss0, ss1, ss2,
                       m00, m01, m02, m10, m11, m12, m20, m21, m22};
#pragma unroll
    for (int k = 0; k < 16; ++k) {
      double x = vals[k];
      for (int o = 32; o; o >>= 1) x += __shfl_down(x, o, 64);
      if (lane == 0) red[tid >> 6][k] = x;
    }
    __syncthreads();
    if (tid == 0) {
      double s16[16];
      for (int k = 0; k < 16; ++k)
        s16[k] = red[0][k] + red[1][k] + red[2][k] + red[3][k];
      kabsch_from_sums(s16[0], s16 + 1, s16 + 4, s16 + 7, T);
    }
    __syncthreads();
  }
  if (tid == 0) {
    out[10500 + 0]  = (float)T[0]; out[10500 + 1]  = (float)T[1];
    out[10500 + 2]  = (float)T[2]; out[10500 + 3]  = (float)T[9];
    out[10500 + 4]  = (float)T[3]; out[10500 + 5]  = (float)T[4];
    out[10500 + 6]  = (float)T[5]; out[10500 + 7]  = (float)T[10];
    out[10500 + 8]  = (float)T[6]; out[10500 + 9]  = (float)T[7];
    out[10500 + 10] = (float)T[8]; out[10500 + 11] = (float)T[11];
    out[10500 + 12] = 0.f; out[10500 + 13] = 0.f;
    out[10500 + 14] = 0.f; out[10500 + 15] = 1.f;
  }
}

extern "C" void kernel_launch(void* const* d_in, const int* in_sizes, int n_in,
                              void* d_out, int out_size, void* d_ws, size_t ws_size,
                              hipStream_t stream) {
  const float* refp = (const float*)d_in[0];
  const float* srcp = (const float*)d_in[1];
  const void* mref = d_in[2];
  const void* msrc = d_in[3];
  const float* scores = (const float*)d_in[4];
  float* out = (float*)d_out;
  char* ws = (char*)d_ws;
  unsigned* hist = (unsigned*)(ws + OFF_HIST);
  unsigned* hdr = (unsigned*)(ws + OFF_HDR);
  double* stats = (double*)(ws + OFF_STATS);
  double* trans = (double*)(ws + OFF_TRANS);
  int* icount = (int*)(ws + OFF_ICNT);
  float* pool = (float*)(ws + OFF_POOL);
  unsigned long long* cand = (unsigned long long*)(ws + OFF_CAND);
  unsigned long long* sel = (unsigned long long*)(ws + OFF_SEL);

  (void)hipMemsetAsync(ws, 0, OFF_STATS, stream);  // hist + hdr
  k_maskdetect<<<1, 64, 0, stream>>>((const unsigned*)mref, hdr);
  k_fused<<<PP, 256, 0, stream>>>(scores, refp, srcp, mref, msrc, hist, hdr, stats, cand);
  k_cutoff<<<1, 1024, 0, stream>>>(hist, hdr);
  k_compact<<<CAND_CAP / 256, 256, 0, stream>>>(cand, hdr, sel);
  k_sortout<<<1, 1024, 0, stream>>>(sel, hdr, scores, refp, srcp, pool, out);
  k_transforms<<<16, 64, 0, stream>>>(stats, trans);
  k_eval<<<PP, 256, 0, stream>>>(trans, stats, pool, icount);
  k_refine<<<1, 256, 0, stream>>>(trans, icount, pool, out);
}